// Round 1
// baseline (1725.015 us; speedup 1.0000x reference)
//
#include <hip/hip_runtime.h>

#define D 128
#define D3 384
#define EDIM 20
#define NR 3
#define NG 3
#define CUTOFF 5.0f
#define NNODES 10000
#define NEDGES 160000
#define NMOL 500
#define HROH 64
#define PI_F 3.14159265358979323846f

#define FBIAS 1
#define FSILU 2
#define FACC 4

static __device__ __forceinline__ float silu_f(float x) {
    return x / (1.0f + expf(-x));
}

// ---------------------------------------------------------------------------
// Generic f32 GEMM: C[n,m] (+)= act(A[n,:] @ W[:,m] + bias[m])
// 64x64 tile, 256 threads, 4x4 micro-tile, K-chunks of 16.
// grid.z with element strides zsA/zsC handles the per-coordinate v GEMMs.
// ---------------------------------------------------------------------------
__global__ __launch_bounds__(256) void gemm_k(
    const float* __restrict__ A, int lda, int zsA,
    const float* __restrict__ W, int ldw,
    const float* __restrict__ bias,
    float* __restrict__ C, int ldc, int zsC,
    int N, int K, int flags)
{
    A += (size_t)blockIdx.z * zsA;
    C += (size_t)blockIdx.z * zsC;
    const int n0 = blockIdx.x * 64;
    const int m0 = blockIdx.y * 64;
    __shared__ float As[16][64];
    __shared__ float Bs[16][64];
    const int tid = threadIdx.x;
    const int tx = tid & 15;
    const int ty = tid >> 4;
    const int arow = tid >> 2;        // 0..63
    const int akb  = (tid & 3) * 4;   // 0,4,8,12
    const int brow = tid >> 4;        // 0..15
    const int bcol = (tid & 15) * 4;
    const bool aval = (n0 + arow) < N;
    const float* Aptr = A + (size_t)(n0 + arow) * lda + akb;
    const float* Wptr = W + (size_t)brow * ldw + m0 + bcol;
    float acc[4][4] = {};
    for (int k0 = 0; k0 < K; k0 += 16) {
        float4 av = aval ? *(const float4*)(Aptr + k0) : make_float4(0.f, 0.f, 0.f, 0.f);
        float4 bv = *(const float4*)(Wptr + (size_t)k0 * ldw);
        As[akb + 0][arow] = av.x;
        As[akb + 1][arow] = av.y;
        As[akb + 2][arow] = av.z;
        As[akb + 3][arow] = av.w;
        *(float4*)&Bs[brow][bcol] = bv;
        __syncthreads();
        #pragma unroll
        for (int kk = 0; kk < 16; ++kk) {
            float4 a = *(const float4*)&As[kk][ty * 4];
            float4 b = *(const float4*)&Bs[kk][tx * 4];
            float ar[4] = {a.x, a.y, a.z, a.w};
            float br[4] = {b.x, b.y, b.z, b.w};
            #pragma unroll
            for (int i = 0; i < 4; ++i)
                #pragma unroll
                for (int j = 0; j < 4; ++j)
                    acc[i][j] = fmaf(ar[i], br[j], acc[i][j]);
        }
        __syncthreads();
    }
    #pragma unroll
    for (int i = 0; i < 4; ++i) {
        int n = n0 + ty * 4 + i;
        if (n >= N) break;
        float* Crow = C + (size_t)n * ldc + m0;
        #pragma unroll
        for (int j = 0; j < 4; ++j) {
            int m = m0 + tx * 4 + j;
            float val = acc[i][j];
            if (flags & FBIAS) val += bias[m];
            if (flags & FACC)  val += Crow[tx * 4 + j];
            if (flags & FSILU) val = silu_f(val);
            Crow[tx * 4 + j] = val;
        }
    }
}

// ---------------------------------------------------------------------------
// s = h @ emb_w + emb_b   (K=5)
// ---------------------------------------------------------------------------
__global__ __launch_bounds__(256) void emb_k(
    const float* __restrict__ h, const float* __restrict__ w,
    const float* __restrict__ b, float* __restrict__ s, int total)
{
    int i = blockIdx.x * 256 + threadIdx.x;
    if (i >= total) return;
    int n = i >> 7, d = i & 127;
    float acc = b[d];
    #pragma unroll
    for (int k = 0; k < 5; ++k) acc = fmaf(h[n * 5 + k], w[k * D + d], acc);
    s[i] = acc;
}

// ---------------------------------------------------------------------------
// Per-edge geometry: unit vector, cosine cutoff, sinc RBF.
// ---------------------------------------------------------------------------
__global__ __launch_bounds__(256) void edge_pre_k(
    const int* __restrict__ ei, const float* __restrict__ pos,
    float* __restrict__ rbf, float* __restrict__ uf, int E)
{
    int e = blockIdx.x * 256 + threadIdx.x;
    if (e >= E) return;
    int r = ei[e], c = ei[E + e];
    float dx = pos[c * 3 + 0] - pos[r * 3 + 0];
    float dy = pos[c * 3 + 1] - pos[r * 3 + 1];
    float dz = pos[c * 3 + 2] - pos[r * 3 + 2];
    float dist = sqrtf(dx * dx + dy * dy + dz * dz);
    float d = fmaxf(dist, 1e-6f);
    float inv = 1.0f / d;
    uf[e * 4 + 0] = dx * inv;
    uf[e * 4 + 1] = dy * inv;
    uf[e * 4 + 2] = dz * inv;
    uf[e * 4 + 3] = (d < CUTOFF) ? 0.5f * (cosf(PI_F * d / CUTOFF) + 1.0f) : 0.0f;
    float w = PI_F * d / CUTOFF;
    #pragma unroll
    for (int k = 1; k <= EDIM; ++k)
        rbf[e * EDIM + (k - 1)] = sinf((float)k * w) * inv;
}

// ---------------------------------------------------------------------------
// Message pass: per edge, filt = (rbf@Wf + bf)*fcut; x = phi[col]*filt;
// scatter xs into s[row] and (xvv*v[col] + xvw*unit) into DV[row] via atomics.
// 256 threads = 2 edges x 128 features. Filter weights staged in LDS (32 KB).
// ---------------------------------------------------------------------------
__global__ __launch_bounds__(256) void message_k(
    const int* __restrict__ ei,
    const float* __restrict__ rbf, const float* __restrict__ uf,
    const float* __restrict__ P, const float* __restrict__ vold,
    const float* __restrict__ Wf, const float* __restrict__ bf,
    float* __restrict__ s, float* __restrict__ DV, int E)
{
    __shared__ float wf[EDIM * D3];
    __shared__ float bfs[D3];
    for (int i = threadIdx.x; i < EDIM * D3; i += 256) wf[i] = Wf[i];
    for (int i = threadIdx.x; i < D3; i += 256) bfs[i] = bf[i];
    __syncthreads();
    const int EPB = 32;
    int e0 = blockIdx.x * EPB;
    int sub = threadIdx.x >> 7;
    int d = threadIdx.x & 127;
    for (int i = 0; i < EPB; i += 2) {
        int e = e0 + i + sub;
        if (e >= E) continue;
        float fc = uf[e * 4 + 3];
        if (fc == 0.0f) continue;
        int row = ei[e], col = ei[E + e];
        float fs  = bfs[d];
        float fvv = bfs[D + d];
        float fvw = bfs[2 * D + d];
        const float* rb = rbf + (size_t)e * EDIM;
        #pragma unroll
        for (int k = 0; k < EDIM; ++k) {
            float rv = rb[k];
            fs  = fmaf(rv, wf[k * D3 + d], fs);
            fvv = fmaf(rv, wf[k * D3 + D + d], fvv);
            fvw = fmaf(rv, wf[k * D3 + 2 * D + d], fvw);
        }
        const float* pc = P + (size_t)col * D3;
        float xs  = pc[d] * fs * fc;
        float xvv = pc[D + d] * fvv * fc;
        float xvw = pc[2 * D + d] * fvw * fc;
        float ux = uf[e * 4 + 0], uy = uf[e * 4 + 1], uz = uf[e * 4 + 2];
        const float* vc = vold + (size_t)col * D3;
        atomicAdd(s + (size_t)row * D + d, xs);
        float* dvr = DV + (size_t)row * D3;
        atomicAdd(dvr + d,         fmaf(xvv, vc[d], xvw * ux));
        atomicAdd(dvr + D + d,     fmaf(xvv, vc[D + d], xvw * uy));
        atomicAdd(dvr + 2 * D + d, fmaf(xvv, vc[2 * D + d], xvw * uz));
    }
}

__global__ __launch_bounds__(256) void vadd_k(float* __restrict__ v,
                                              const float* __restrict__ dv, int total)
{
    int i = blockIdx.x * 256 + threadIdx.x;
    if (i < total) v[i] += dv[i];
}

// Vn[n,d] = sqrt(sum_c V3[n,c,d]^2 + 1e-8)
__global__ __launch_bounds__(256) void norm3_k(const float* __restrict__ V3,
                                               float* __restrict__ Vn, int total)
{
    int i = blockIdx.x * 256 + threadIdx.x;
    if (i >= total) return;
    int n = i >> 7, d = i & 127;
    const float* b = V3 + (size_t)n * D3;
    float x = b[d], y = b[D + d], z = b[2 * D + d];
    Vn[i] = sqrtf(fmaf(x, x, fmaf(y, y, fmaf(z, z, 1e-8f))));
}

// s += a_ss + a_sv * <Uv,Vv>;  v += a_vv * Uv
__global__ __launch_bounds__(256) void upd_apply_k(
    const float* __restrict__ U3, const float* __restrict__ V3,
    const float* __restrict__ P, float* __restrict__ s,
    float* __restrict__ v, int total)
{
    int i = blockIdx.x * 256 + threadIdx.x;
    if (i >= total) return;
    int n = i >> 7, d = i & 127;
    const float* u = U3 + (size_t)n * D3;
    const float* w = V3 + (size_t)n * D3;
    float ux = u[d], uy = u[D + d], uz = u[2 * D + d];
    float vx = w[d], vy = w[D + d], vz = w[2 * D + d];
    float dot = fmaf(ux, vx, fmaf(uy, vy, uz * vz));
    const float* a = P + (size_t)n * D3;
    s[i] += a[d] + a[D + d] * dot;
    float avv = a[2 * D + d];
    float* vv = v + (size_t)n * D3;
    vv[d]         = fmaf(avv, ux, vv[d]);
    vv[D + d]     = fmaf(avv, uy, vv[D + d]);
    vv[2 * D + d] = fmaf(avv, uz, vv[2 * D + d]);
}

// s = a[:, :D];  v = a[:, D:2D, None] * v1
__global__ __launch_bounds__(256) void geb_apply_k(
    const float* __restrict__ P, const float* __restrict__ U3,
    float* __restrict__ s, float* __restrict__ v, int total)
{
    int i = blockIdx.x * 256 + threadIdx.x;
    if (i >= total) return;
    int n = i >> 7, d = i & 127;
    const float* a = P + (size_t)n * 2 * D;
    s[i] = a[d];
    float g = a[D + d];
    const float* u = U3 + (size_t)n * D3;
    float* vv = v + (size_t)n * D3;
    vv[d]         = g * u[d];
    vv[D + d]     = g * u[D + d];
    vv[2 * D + d] = g * u[2 * D + d];
}

// out[batch[n]] += hidden[n] @ ro_w2 + ro_b2
__global__ __launch_bounds__(256) void readout_k(
    const float* __restrict__ H2, const float* __restrict__ w2,
    const float* __restrict__ b2, const int* __restrict__ batch,
    float* __restrict__ out, int N)
{
    int n = blockIdx.x * 256 + threadIdx.x;
    if (n >= N) return;
    float acc = b2[0];
    const float* hrow = H2 + (size_t)n * HROH;
    #pragma unroll
    for (int k = 0; k < HROH; ++k) acc = fmaf(hrow[k], w2[k], acc);
    atomicAdd(out + batch[n], acc);
}

// ---------------------------------------------------------------------------

static inline void gemm(hipStream_t st, const float* A, int lda, int zsA,
                        const float* W, int ldw, const float* bias,
                        float* C, int ldc, int zsC,
                        int N, int K, int M, int flags, int Z = 1)
{
    dim3 g((N + 63) / 64, M / 64, Z);
    hipLaunchKernelGGL(gemm_k, g, dim3(256), 0, st,
                       A, lda, zsA, W, ldw, bias, C, ldc, zsC, N, K, flags);
}

extern "C" void kernel_launch(void* const* d_in, const int* in_sizes, int n_in,
                              void* d_out, int out_size, void* d_ws, size_t ws_size,
                              hipStream_t stream)
{
    const float* h          = (const float*)d_in[0];
    const float* pos        = (const float*)d_in[1];
    const int*   ei         = (const int*)d_in[2];
    const int*   batch      = (const int*)d_in[3];
    const float* emb_w      = (const float*)d_in[4];
    const float* emb_b      = (const float*)d_in[5];
    const float* msg_phi_w1 = (const float*)d_in[6];
    const float* msg_phi_b1 = (const float*)d_in[7];
    const float* msg_phi_w2 = (const float*)d_in[8];
    const float* msg_phi_b2 = (const float*)d_in[9];
    const float* msg_filt_w = (const float*)d_in[10];
    const float* msg_filt_b = (const float*)d_in[11];
    const float* upd_U      = (const float*)d_in[12];
    const float* upd_V      = (const float*)d_in[13];
    const float* upd_w1     = (const float*)d_in[14];
    const float* upd_b1     = (const float*)d_in[15];
    const float* upd_w2     = (const float*)d_in[16];
    const float* upd_b2     = (const float*)d_in[17];
    const float* geb_wv1    = (const float*)d_in[18];
    const float* geb_wv2    = (const float*)d_in[19];
    const float* geb_w1     = (const float*)d_in[20];
    const float* geb_b1     = (const float*)d_in[21];
    const float* geb_w2     = (const float*)d_in[22];
    const float* geb_b2     = (const float*)d_in[23];
    const float* ro_w1      = (const float*)d_in[24];
    const float* ro_b1      = (const float*)d_in[25];
    const float* ro_w2      = (const float*)d_in[26];
    const float* ro_b2      = (const float*)d_in[27];
    float* out = (float*)d_out;

    const int N = NNODES, E = NEDGES;

    char* p = (char*)d_ws;
    auto carve = [&](size_t elems) {
        float* r = (float*)p;
        p += ((elems * 4) + 255) & ~(size_t)255;
        return r;
    };
    float* S   = carve((size_t)N * D);    // scalar state
    float* V   = carve((size_t)N * D3);   // vector state [N,3,D]
    float* P   = carve((size_t)N * D3);   // phi / a buffer
    float* H   = carve((size_t)N * D);    // hidden / Vn
    float* H2  = carve((size_t)N * D);    // second hidden
    float* U3  = carve((size_t)N * D3);   // Uv / v1 / DV accumulator
    float* V3  = carve((size_t)N * D3);   // Vv / v2
    float* RBF = carve((size_t)E * EDIM);
    float* UF  = carve((size_t)E * 4);    // unit xyz + fcut

    // init: s = emb(h), v = 0, edge geometry
    hipMemsetAsync(V, 0, (size_t)N * D3 * 4, stream);
    hipLaunchKernelGGL(emb_k, dim3((N * D + 255) / 256), dim3(256), 0, stream,
                       h, emb_w, emb_b, S, N * D);
    hipLaunchKernelGGL(edge_pre_k, dim3((E + 255) / 256), dim3(256), 0, stream,
                       ei, pos, RBF, UF, E);

    for (int r = 0; r < NR; ++r) {
        // phi = silu(s@W1+b1)@W2+b2
        gemm(stream, S, D, 0, msg_phi_w1 + (size_t)r * D * D, D,
             msg_phi_b1 + (size_t)r * D, H, D, 0, N, D, D, FBIAS | FSILU);
        gemm(stream, H, D, 0, msg_phi_w2 + (size_t)r * D * D3, D3,
             msg_phi_b2 + (size_t)r * D3, P, D3, 0, N, D, D3, FBIAS);
        // message scatter (DV aliases U3)
        hipMemsetAsync(U3, 0, (size_t)N * D3 * 4, stream);
        hipLaunchKernelGGL(message_k, dim3(E / 32), dim3(256), 0, stream,
                           ei, RBF, UF, P, V,
                           msg_filt_w + (size_t)r * EDIM * D3,
                           msg_filt_b + (size_t)r * D3, S, U3, E);
        hipLaunchKernelGGL(vadd_k, dim3((N * D3 + 255) / 256), dim3(256), 0, stream,
                           V, U3, N * D3);
        // update
        gemm(stream, V, D3, D, upd_U + (size_t)r * D * D, D, nullptr,
             U3, D3, D, N, D, D, 0, 3);
        gemm(stream, V, D3, D, upd_V + (size_t)r * D * D, D, nullptr,
             V3, D3, D, N, D, D, 0, 3);
        hipLaunchKernelGGL(norm3_k, dim3((N * D + 255) / 256), dim3(256), 0, stream,
                           V3, H, N * D);
        gemm(stream, S, D, 0, upd_w1 + (size_t)r * 2 * D * D, D,
             upd_b1 + (size_t)r * D, H2, D, 0, N, D, D, FBIAS);
        gemm(stream, H, D, 0, upd_w1 + (size_t)r * 2 * D * D + D * D, D,
             nullptr, H2, D, 0, N, D, D, FACC | FSILU);
        gemm(stream, H2, D, 0, upd_w2 + (size_t)r * D * D3, D3,
             upd_b2 + (size_t)r * D3, P, D3, 0, N, D, D3, FBIAS);
        hipLaunchKernelGGL(upd_apply_k, dim3((N * D + 255) / 256), dim3(256), 0, stream,
                           U3, V3, P, S, V, N * D);
    }

    for (int g = 0; g < NG; ++g) {
        gemm(stream, V, D3, D, geb_wv1 + (size_t)g * D * D, D, nullptr,
             U3, D3, D, N, D, D, 0, 3);
        gemm(stream, V, D3, D, geb_wv2 + (size_t)g * D * D, D, nullptr,
             V3, D3, D, N, D, D, 0, 3);
        hipLaunchKernelGGL(norm3_k, dim3((N * D + 255) / 256), dim3(256), 0, stream,
                           V3, H, N * D);
        gemm(stream, S, D, 0, geb_w1 + (size_t)g * 2 * D * D, D,
             geb_b1 + (size_t)g * D, H2, D, 0, N, D, D, FBIAS);
        gemm(stream, H, D, 0, geb_w1 + (size_t)g * 2 * D * D + D * D, D,
             nullptr, H2, D, 0, N, D, D, FACC | FSILU);
        gemm(stream, H2, D, 0, geb_w2 + (size_t)g * D * 2 * D, 2 * D,
             geb_b2 + (size_t)g * 2 * D, P, 2 * D, 0, N, D, 2 * D, FBIAS);
        hipLaunchKernelGGL(geb_apply_k, dim3((N * D + 255) / 256), dim3(256), 0, stream,
                           P, U3, S, V, N * D);
    }

    // readout
    gemm(stream, S, D, 0, ro_w1, HROH, ro_b1, H2, HROH, 0, N, D, HROH, FBIAS | FSILU);
    hipMemsetAsync(out, 0, (size_t)NMOL * 4, stream);
    hipLaunchKernelGGL(readout_k, dim3((N + 255) / 256), dim3(256), 0, stream,
                       H2, ro_w2, ro_b2, batch, out, N);
}

// Round 2
// 1483.462 us; speedup vs baseline: 1.1628x; 1.1628x over previous
//
#include <hip/hip_runtime.h>

#define D 128
#define D3 384
#define EDIM 20
#define NR 3
#define NG 3
#define CUTOFF 5.0f
#define NNODES 10000
#define NEDGES 160000
#define NMOL 500
#define HROH 64
#define PI_F 3.14159265358979323846f

#define FBIAS 1
#define FSILU 2
#define FACC 4

static __device__ __forceinline__ float silu_f(float x) {
    return x / (1.0f + expf(-x));
}

// ---------------------------------------------------------------------------
// Generic f32 GEMM: C[n,m] (+)= act(A[n,:] @ W[:,m] + bias[m])
// 64x64 tile, 256 threads, 4x4 micro-tile, K-chunks of 16.
// grid.z with element strides zsA/zsC handles the per-coordinate v GEMMs.
// ---------------------------------------------------------------------------
__global__ __launch_bounds__(256) void gemm_k(
    const float* __restrict__ A, int lda, int zsA,
    const float* __restrict__ W, int ldw,
    const float* __restrict__ bias,
    float* __restrict__ C, int ldc, int zsC,
    int N, int K, int flags)
{
    A += (size_t)blockIdx.z * zsA;
    C += (size_t)blockIdx.z * zsC;
    const int n0 = blockIdx.x * 64;
    const int m0 = blockIdx.y * 64;
    __shared__ float As[16][64];
    __shared__ float Bs[16][64];
    const int tid = threadIdx.x;
    const int tx = tid & 15;
    const int ty = tid >> 4;
    const int arow = tid >> 2;        // 0..63
    const int akb  = (tid & 3) * 4;   // 0,4,8,12
    const int brow = tid >> 4;        // 0..15
    const int bcol = (tid & 15) * 4;
    const bool aval = (n0 + arow) < N;
    const float* Aptr = A + (size_t)(n0 + arow) * lda + akb;
    const float* Wptr = W + (size_t)brow * ldw + m0 + bcol;
    float acc[4][4] = {};
    for (int k0 = 0; k0 < K; k0 += 16) {
        float4 av = aval ? *(const float4*)(Aptr + k0) : make_float4(0.f, 0.f, 0.f, 0.f);
        float4 bv = *(const float4*)(Wptr + (size_t)k0 * ldw);
        As[akb + 0][arow] = av.x;
        As[akb + 1][arow] = av.y;
        As[akb + 2][arow] = av.z;
        As[akb + 3][arow] = av.w;
        *(float4*)&Bs[brow][bcol] = bv;
        __syncthreads();
        #pragma unroll
        for (int kk = 0; kk < 16; ++kk) {
            float4 a = *(const float4*)&As[kk][ty * 4];
            float4 b = *(const float4*)&Bs[kk][tx * 4];
            float ar[4] = {a.x, a.y, a.z, a.w};
            float br[4] = {b.x, b.y, b.z, b.w};
            #pragma unroll
            for (int i = 0; i < 4; ++i)
                #pragma unroll
                for (int j = 0; j < 4; ++j)
                    acc[i][j] = fmaf(ar[i], br[j], acc[i][j]);
        }
        __syncthreads();
    }
    #pragma unroll
    for (int i = 0; i < 4; ++i) {
        int n = n0 + ty * 4 + i;
        if (n >= N) break;
        float* Crow = C + (size_t)n * ldc + m0;
        #pragma unroll
        for (int j = 0; j < 4; ++j) {
            int m = m0 + tx * 4 + j;
            float val = acc[i][j];
            if (flags & FBIAS) val += bias[m];
            if (flags & FACC)  val += Crow[tx * 4 + j];
            if (flags & FSILU) val = silu_f(val);
            Crow[tx * 4 + j] = val;
        }
    }
}

// ---------------------------------------------------------------------------
// s = h @ emb_w + emb_b   (K=5)
// ---------------------------------------------------------------------------
__global__ __launch_bounds__(256) void emb_k(
    const float* __restrict__ h, const float* __restrict__ w,
    const float* __restrict__ b, float* __restrict__ s, int total)
{
    int i = blockIdx.x * 256 + threadIdx.x;
    if (i >= total) return;
    int n = i >> 7, d = i & 127;
    float acc = b[d];
    #pragma unroll
    for (int k = 0; k < 5; ++k) acc = fmaf(h[n * 5 + k], w[k * D + d], acc);
    s[i] = acc;
}

// ---------------------------------------------------------------------------
// Per-edge geometry: unit vector, cosine cutoff, sinc RBF.
// ---------------------------------------------------------------------------
__global__ __launch_bounds__(256) void edge_pre_k(
    const int* __restrict__ ei, const float* __restrict__ pos,
    float* __restrict__ rbf, float* __restrict__ uf, int E)
{
    int e = blockIdx.x * 256 + threadIdx.x;
    if (e >= E) return;
    int r = ei[e], c = ei[E + e];
    float dx = pos[c * 3 + 0] - pos[r * 3 + 0];
    float dy = pos[c * 3 + 1] - pos[r * 3 + 1];
    float dz = pos[c * 3 + 2] - pos[r * 3 + 2];
    float dist = sqrtf(dx * dx + dy * dy + dz * dz);
    float d = fmaxf(dist, 1e-6f);
    float inv = 1.0f / d;
    uf[e * 4 + 0] = dx * inv;
    uf[e * 4 + 1] = dy * inv;
    uf[e * 4 + 2] = dz * inv;
    uf[e * 4 + 3] = (d < CUTOFF) ? 0.5f * (cosf(PI_F * d / CUTOFF) + 1.0f) : 0.0f;
    float w = PI_F * d / CUTOFF;
    #pragma unroll
    for (int k = 1; k <= EDIM; ++k)
        rbf[e * EDIM + (k - 1)] = sinf((float)k * w) * inv;
}

// ---------------------------------------------------------------------------
// CSR construction (in-kernel, once per launch)
// ---------------------------------------------------------------------------
__global__ __launch_bounds__(256) void hist_k(const int* __restrict__ ei,
                                              int* __restrict__ cnt, int E)
{
    int e = blockIdx.x * 256 + threadIdx.x;
    if (e < E) atomicAdd(&cnt[ei[e]], 1);
}

// single-block exclusive scan: offs[0]=0, offs[i+1]=sum cnt[0..i]
__global__ __launch_bounds__(256) void scan_k(const int* __restrict__ cnt,
                                              int* __restrict__ offs, int n)
{
    __shared__ int tmp[256];
    __shared__ int carry;
    if (threadIdx.x == 0) carry = 0;
    __syncthreads();
    for (int base = 0; base < n; base += 256) {
        int i = base + threadIdx.x;
        int v = (i < n) ? cnt[i] : 0;
        tmp[threadIdx.x] = v;
        __syncthreads();
        for (int off = 1; off < 256; off <<= 1) {
            int add = (threadIdx.x >= off) ? tmp[threadIdx.x - off] : 0;
            __syncthreads();
            tmp[threadIdx.x] += add;
            __syncthreads();
        }
        if (i < n) offs[i + 1] = carry + tmp[threadIdx.x];
        __syncthreads();
        if (threadIdx.x == 255) carry += tmp[255];
        __syncthreads();
    }
    if (threadIdx.x == 0) offs[0] = 0;
}

__global__ __launch_bounds__(256) void initnext_k(const int* __restrict__ offs,
                                                  int* __restrict__ next, int n)
{
    int i = blockIdx.x * 256 + threadIdx.x;
    if (i < n) next[i] = offs[i];
}

__global__ __launch_bounds__(256) void scatter_k(const int* __restrict__ ei,
                                                 int* __restrict__ next,
                                                 int* __restrict__ eid, int E)
{
    int e = blockIdx.x * 256 + threadIdx.x;
    if (e < E) {
        int p = atomicAdd(&next[ei[e]], 1);
        eid[p] = e;
    }
}

// ---------------------------------------------------------------------------
// CSR message pass: one node per 128-thread sub-group, register accumulation.
// filt = (rbf@Wf + bf)*fcut; x = phi[col]*filt;
// S[n] += sum xs;  Vnew[n] = Vold[n] + sum(xvv*Vold[col] + xvw*unit)
// Filter weights staged in LDS (~31 KB -> 5 blocks/CU).
// ---------------------------------------------------------------------------
#define MSG_NPB 8
__global__ __launch_bounds__(256) void message_csr_k(
    const int* __restrict__ ei, const int* __restrict__ offs,
    const int* __restrict__ eid,
    const float* __restrict__ rbf, const float* __restrict__ uf,
    const float* __restrict__ P, const float* __restrict__ Vold,
    const float* __restrict__ Wf, const float* __restrict__ bf,
    float* __restrict__ S, float* __restrict__ Vnew, int N, int E)
{
    __shared__ float wf[EDIM * D3];
    __shared__ float bfs[D3];
    for (int i = threadIdx.x; i < EDIM * D3; i += 256) wf[i] = Wf[i];
    for (int i = threadIdx.x; i < D3; i += 256) bfs[i] = bf[i];
    __syncthreads();
    const int sub = threadIdx.x >> 7;
    const int d = threadIdx.x & 127;
    for (int it = 0; it < MSG_NPB / 2; ++it) {
        int n = blockIdx.x * MSG_NPB + it * 2 + sub;
        if (n >= N) break;   // no __syncthreads below: divergence safe
        float ds = 0.f, dvx = 0.f, dvy = 0.f, dvz = 0.f;
        int j1 = offs[n + 1];
        for (int j = offs[n]; j < j1; ++j) {
            int e = eid[j];
            float4 u4 = *(const float4*)(uf + (size_t)e * 4);
            float fc = u4.w;
            if (fc == 0.0f) continue;
            int col = ei[E + e];
            float fs  = bfs[d];
            float fvv = bfs[D + d];
            float fvw = bfs[2 * D + d];
            const float* rb = rbf + (size_t)e * EDIM;
            #pragma unroll
            for (int k = 0; k < EDIM; ++k) {
                float rv = rb[k];
                fs  = fmaf(rv, wf[k * D3 + d], fs);
                fvv = fmaf(rv, wf[k * D3 + D + d], fvv);
                fvw = fmaf(rv, wf[k * D3 + 2 * D + d], fvw);
            }
            const float* pc = P + (size_t)col * D3;
            const float* vc = Vold + (size_t)col * D3;
            float xs  = pc[d] * fs * fc;
            float xvv = pc[D + d] * fvv * fc;
            float xvw = pc[2 * D + d] * fvw * fc;
            ds += xs;
            dvx = fmaf(xvv, vc[d],         fmaf(xvw, u4.x, dvx));
            dvy = fmaf(xvv, vc[D + d],     fmaf(xvw, u4.y, dvy));
            dvz = fmaf(xvv, vc[2 * D + d], fmaf(xvw, u4.z, dvz));
        }
        S[(size_t)n * D + d] += ds;
        const float* vo = Vold + (size_t)n * D3;
        float* vn = Vnew + (size_t)n * D3;
        vn[d]         = vo[d] + dvx;
        vn[D + d]     = vo[D + d] + dvy;
        vn[2 * D + d] = vo[2 * D + d] + dvz;
    }
}

// Vn[n,d] = sqrt(sum_c V3[n,c,d]^2 + 1e-8)
__global__ __launch_bounds__(256) void norm3_k(const float* __restrict__ V3,
                                               float* __restrict__ Vn, int total)
{
    int i = blockIdx.x * 256 + threadIdx.x;
    if (i >= total) return;
    int n = i >> 7, d = i & 127;
    const float* b = V3 + (size_t)n * D3;
    float x = b[d], y = b[D + d], z = b[2 * D + d];
    Vn[i] = sqrtf(fmaf(x, x, fmaf(y, y, fmaf(z, z, 1e-8f))));
}

// s += a_ss + a_sv * <Uv,Vv>;  v += a_vv * Uv
__global__ __launch_bounds__(256) void upd_apply_k(
    const float* __restrict__ U3, const float* __restrict__ V3,
    const float* __restrict__ P, float* __restrict__ s,
    float* __restrict__ v, int total)
{
    int i = blockIdx.x * 256 + threadIdx.x;
    if (i >= total) return;
    int n = i >> 7, d = i & 127;
    const float* u = U3 + (size_t)n * D3;
    const float* w = V3 + (size_t)n * D3;
    float ux = u[d], uy = u[D + d], uz = u[2 * D + d];
    float vx = w[d], vy = w[D + d], vz = w[2 * D + d];
    float dot = fmaf(ux, vx, fmaf(uy, vy, uz * vz));
    const float* a = P + (size_t)n * D3;
    s[i] += a[d] + a[D + d] * dot;
    float avv = a[2 * D + d];
    float* vv = v + (size_t)n * D3;
    vv[d]         = fmaf(avv, ux, vv[d]);
    vv[D + d]     = fmaf(avv, uy, vv[D + d]);
    vv[2 * D + d] = fmaf(avv, uz, vv[2 * D + d]);
}

// s = a[:, :D];  v = a[:, D:2D, None] * v1
__global__ __launch_bounds__(256) void geb_apply_k(
    const float* __restrict__ P, const float* __restrict__ U3,
    float* __restrict__ s, float* __restrict__ v, int total)
{
    int i = blockIdx.x * 256 + threadIdx.x;
    if (i >= total) return;
    int n = i >> 7, d = i & 127;
    const float* a = P + (size_t)n * 2 * D;
    s[i] = a[d];
    float g = a[D + d];
    const float* u = U3 + (size_t)n * D3;
    float* vv = v + (size_t)n * D3;
    vv[d]         = g * u[d];
    vv[D + d]     = g * u[D + d];
    vv[2 * D + d] = g * u[2 * D + d];
}

// out[batch[n]] += hidden[n] @ ro_w2 + ro_b2
__global__ __launch_bounds__(256) void readout_k(
    const float* __restrict__ H2, const float* __restrict__ w2,
    const float* __restrict__ b2, const int* __restrict__ batch,
    float* __restrict__ out, int N)
{
    int n = blockIdx.x * 256 + threadIdx.x;
    if (n >= N) return;
    float acc = b2[0];
    const float* hrow = H2 + (size_t)n * HROH;
    #pragma unroll
    for (int k = 0; k < HROH; ++k) acc = fmaf(hrow[k], w2[k], acc);
    atomicAdd(out + batch[n], acc);
}

// ---------------------------------------------------------------------------

static inline void gemm(hipStream_t st, const float* A, int lda, int zsA,
                        const float* W, int ldw, const float* bias,
                        float* C, int ldc, int zsC,
                        int N, int K, int M, int flags, int Z = 1)
{
    dim3 g((N + 63) / 64, M / 64, Z);
    hipLaunchKernelGGL(gemm_k, g, dim3(256), 0, st,
                       A, lda, zsA, W, ldw, bias, C, ldc, zsC, N, K, flags);
}

extern "C" void kernel_launch(void* const* d_in, const int* in_sizes, int n_in,
                              void* d_out, int out_size, void* d_ws, size_t ws_size,
                              hipStream_t stream)
{
    const float* h          = (const float*)d_in[0];
    const float* pos        = (const float*)d_in[1];
    const int*   ei         = (const int*)d_in[2];
    const int*   batch      = (const int*)d_in[3];
    const float* emb_w      = (const float*)d_in[4];
    const float* emb_b      = (const float*)d_in[5];
    const float* msg_phi_w1 = (const float*)d_in[6];
    const float* msg_phi_b1 = (const float*)d_in[7];
    const float* msg_phi_w2 = (const float*)d_in[8];
    const float* msg_phi_b2 = (const float*)d_in[9];
    const float* msg_filt_w = (const float*)d_in[10];
    const float* msg_filt_b = (const float*)d_in[11];
    const float* upd_U      = (const float*)d_in[12];
    const float* upd_V      = (const float*)d_in[13];
    const float* upd_w1     = (const float*)d_in[14];
    const float* upd_b1     = (const float*)d_in[15];
    const float* upd_w2     = (const float*)d_in[16];
    const float* upd_b2     = (const float*)d_in[17];
    const float* geb_wv1    = (const float*)d_in[18];
    const float* geb_wv2    = (const float*)d_in[19];
    const float* geb_w1     = (const float*)d_in[20];
    const float* geb_b1     = (const float*)d_in[21];
    const float* geb_w2     = (const float*)d_in[22];
    const float* geb_b2     = (const float*)d_in[23];
    const float* ro_w1      = (const float*)d_in[24];
    const float* ro_b1      = (const float*)d_in[25];
    const float* ro_w2      = (const float*)d_in[26];
    const float* ro_b2      = (const float*)d_in[27];
    float* out = (float*)d_out;

    const int N = NNODES, E = NEDGES;

    char* p = (char*)d_ws;
    auto carve = [&](size_t bytes) {
        char* r = p;
        p += (bytes + 255) & ~(size_t)255;
        return r;
    };
    float* S    = (float*)carve((size_t)N * D * 4);
    float* VA   = (float*)carve((size_t)N * D3 * 4);
    float* VB   = (float*)carve((size_t)N * D3 * 4);
    float* P_   = (float*)carve((size_t)N * D3 * 4);
    float* H    = (float*)carve((size_t)N * D * 4);
    float* H2   = (float*)carve((size_t)N * D * 4);
    float* V3   = (float*)carve((size_t)N * D3 * 4);
    float* RBF  = (float*)carve((size_t)E * EDIM * 4);
    float* UF   = (float*)carve((size_t)E * 4 * 4);
    int*   offs = (int*)carve((size_t)(N + 1) * 4);
    int*   nxt  = (int*)carve((size_t)N * 4);
    int*   eidb = (int*)carve((size_t)E * 4);

    // init: s = emb(h), v = 0, edge geometry, CSR
    hipMemsetAsync(VA, 0, (size_t)N * D3 * 4, stream);
    hipLaunchKernelGGL(emb_k, dim3((N * D + 255) / 256), dim3(256), 0, stream,
                       h, emb_w, emb_b, S, N * D);
    hipLaunchKernelGGL(edge_pre_k, dim3((E + 255) / 256), dim3(256), 0, stream,
                       ei, pos, RBF, UF, E);
    hipMemsetAsync(nxt, 0, (size_t)N * 4, stream);
    hipLaunchKernelGGL(hist_k, dim3((E + 255) / 256), dim3(256), 0, stream, ei, nxt, E);
    hipLaunchKernelGGL(scan_k, dim3(1), dim3(256), 0, stream, nxt, offs, N);
    hipLaunchKernelGGL(initnext_k, dim3((N + 255) / 256), dim3(256), 0, stream,
                       offs, nxt, N);
    hipLaunchKernelGGL(scatter_k, dim3((E + 255) / 256), dim3(256), 0, stream,
                       ei, nxt, eidb, E);

    float* Vc = VA;   // current v state
    float* Vs = VB;   // spare (message target / dead-buffer scratch)

    for (int r = 0; r < NR; ++r) {
        // phi = silu(s@W1+b1)@W2+b2
        gemm(stream, S, D, 0, msg_phi_w1 + (size_t)r * D * D, D,
             msg_phi_b1 + (size_t)r * D, H, D, 0, N, D, D, FBIAS | FSILU);
        gemm(stream, H, D, 0, msg_phi_w2 + (size_t)r * D * D3, D3,
             msg_phi_b2 + (size_t)r * D3, P_, D3, 0, N, D, D3, FBIAS);
        // message: read Vc, write Vs (= Vc + dv); S += ds
        hipLaunchKernelGGL(message_csr_k, dim3((N + MSG_NPB - 1) / MSG_NPB),
                           dim3(256), 0, stream,
                           ei, offs, eidb, RBF, UF, P_, Vc,
                           msg_filt_w + (size_t)r * EDIM * D3,
                           msg_filt_b + (size_t)r * D3, S, Vs, N, E);
        { float* t = Vc; Vc = Vs; Vs = t; }   // Vc = new state, Vs = dead
        float* Uv = Vs;                       // reuse dead buffer for Uv
        // update
        gemm(stream, Vc, D3, D, upd_U + (size_t)r * D * D, D, nullptr,
             Uv, D3, D, N, D, D, 0, 3);
        gemm(stream, Vc, D3, D, upd_V + (size_t)r * D * D, D, nullptr,
             V3, D3, D, N, D, D, 0, 3);
        hipLaunchKernelGGL(norm3_k, dim3((N * D + 255) / 256), dim3(256), 0, stream,
                           V3, H, N * D);
        gemm(stream, S, D, 0, upd_w1 + (size_t)r * 2 * D * D, D,
             upd_b1 + (size_t)r * D, H2, D, 0, N, D, D, FBIAS);
        gemm(stream, H, D, 0, upd_w1 + (size_t)r * 2 * D * D + D * D, D,
             nullptr, H2, D, 0, N, D, D, FACC | FSILU);
        gemm(stream, H2, D, 0, upd_w2 + (size_t)r * D * D3, D3,
             upd_b2 + (size_t)r * D3, P_, D3, 0, N, D, D3, FBIAS);
        hipLaunchKernelGGL(upd_apply_k, dim3((N * D + 255) / 256), dim3(256), 0, stream,
                           Uv, V3, P_, S, Vc, N * D);
    }

    for (int g = 0; g < NG; ++g) {
        float* Uv = Vs;   // dead buffer as v1 scratch
        gemm(stream, Vc, D3, D, geb_wv1 + (size_t)g * D * D, D, nullptr,
             Uv, D3, D, N, D, D, 0, 3);
        gemm(stream, Vc, D3, D, geb_wv2 + (size_t)g * D * D, D, nullptr,
             V3, D3, D, N, D, D, 0, 3);
        hipLaunchKernelGGL(norm3_k, dim3((N * D + 255) / 256), dim3(256), 0, stream,
                           V3, H, N * D);
        gemm(stream, S, D, 0, geb_w1 + (size_t)g * 2 * D * D, D,
             geb_b1 + (size_t)g * D, H2, D, 0, N, D, D, FBIAS);
        gemm(stream, H, D, 0, geb_w1 + (size_t)g * 2 * D * D + D * D, D,
             nullptr, H2, D, 0, N, D, D, FACC | FSILU);
        gemm(stream, H2, D, 0, geb_w2 + (size_t)g * D * 2 * D, 2 * D,
             geb_b2 + (size_t)g * 2 * D, P_, 2 * D, 0, N, D, 2 * D, FBIAS);
        hipLaunchKernelGGL(geb_apply_k, dim3((N * D + 255) / 256), dim3(256), 0, stream,
                           P_, Uv, S, Vc, N * D);
    }

    // readout
    gemm(stream, S, D, 0, ro_w1, HROH, ro_b1, H2, HROH, 0, N, D, HROH, FBIAS | FSILU);
    hipMemsetAsync(out, 0, (size_t)NMOL * 4, stream);
    hipLaunchKernelGGL(readout_k, dim3((N + 255) / 256), dim3(256), 0, stream,
                       H2, ro_w2, ro_b2, batch, out, N);
}

// Round 3
// 1186.701 us; speedup vs baseline: 1.4536x; 1.2501x over previous
//
#include <hip/hip_runtime.h>

typedef __attribute__((ext_vector_type(4))) float f32x4;
typedef __attribute__((ext_vector_type(8))) short short8;

#define D 128
#define D3 384
#define EDIM 20
#define NR 3
#define NG 3
#define CUTOFF 5.0f
#define NNODES 10000
#define NEDGES 160000
#define NMOL 500
#define HROH 64
#define PI_F 3.14159265358979323846f

#define FBIAS 1
#define FSILU 2
#define FACC 4

static __device__ __forceinline__ float silu_f(float x) {
    return x / (1.0f + expf(-x));
}

// bf16 split helpers (round-to-nearest-even)
static __device__ __forceinline__ ushort f2bf(float x) {
    uint u = __float_as_uint(x);
    uint r = (u + 0x7fffu + ((u >> 16) & 1u)) >> 16;
    return (ushort)r;
}
static __device__ __forceinline__ float bf2f(ushort h) {
    return __uint_as_float((uint)h << 16);
}

// ---------------------------------------------------------------------------
// MFMA bf16x3 GEMM: C[n,m] (+)= act(A[n,:] @ W[:,m] + bias[m])
// f32 inputs split to hi/lo bf16 in staging; acc = ah*bh + al*bh + ah*bl.
// Tile 64x64, 256 threads (4 waves x 16 rows), K-chunk 32, K must be mult 32.
// ---------------------------------------------------------------------------
#define TLR 64
#define TLC 64
#define KC 32
#define APAD 40   // A lds row stride in bf16 (80B: 16B-aligned rows, spread banks)
#define BPAD 36   // B lds row stride in bf16 (72B: 8B-aligned, 16 distinct banks)

__global__ __launch_bounds__(256) void gemm_k(
    const float* __restrict__ A, int lda, int zsA,
    const float* __restrict__ W, int ldw,
    const float* __restrict__ bias,
    float* __restrict__ C, int ldc, int zsC,
    int N, int K, int flags)
{
    A += (size_t)blockIdx.z * zsA;
    C += (size_t)blockIdx.z * zsC;
    const int n0 = blockIdx.x * TLR;
    const int m0 = blockIdx.y * TLC;
    __shared__ ushort Ah[TLR * APAD], Al[TLR * APAD];
    __shared__ ushort Bh[TLC * BPAD], Bl[TLC * BPAD];   // transposed: [col][k]
    const int tid = threadIdx.x;
    // A staging: row = tid&63, k-quad = (tid>>6)*4 (+0 / +16)
    const int arow = tid & 63;
    const int akq = (tid >> 6) * 4;
    const bool aok = (n0 + arow) < N;
    const float* Ar = A + (size_t)(n0 + arow) * lda;
    // B staging: k = tid>>4 (+0 / +16), m = (tid&15)*4
    const int bk = tid >> 4;
    const int bm = (tid & 15) * 4;
    const float* Wp = W + m0 + bm;
    // compute-side indices
    const int lane = tid & 63;
    const int wrow = (tid >> 6) * 16;   // wave's 16-row block
    const int fr = lane & 15;           // frag row (A) / frag col (B) / D col
    const int kg = lane >> 4;           // k-group (8 elems)
    const ushort* aph = Ah + (wrow + fr) * APAD + kg * 8;
    const ushort* apl = Al + (wrow + fr) * APAD + kg * 8;

    f32x4 acc[4];
    #pragma unroll
    for (int t = 0; t < 4; ++t) acc[t] = (f32x4){0.f, 0.f, 0.f, 0.f};

    for (int k0 = 0; k0 < K; k0 += KC) {
        // ---- stage A (hi/lo), packed 4xbf16 = 8B writes
        #pragma unroll
        for (int half = 0; half < 2; ++half) {
            int kk = akq + half * 16;
            float4 v = aok ? *(const float4*)(Ar + k0 + kk)
                           : make_float4(0.f, 0.f, 0.f, 0.f);
            ushort h0 = f2bf(v.x), h1 = f2bf(v.y), h2 = f2bf(v.z), h3 = f2bf(v.w);
            ushort l0 = f2bf(v.x - bf2f(h0)), l1 = f2bf(v.y - bf2f(h1));
            ushort l2 = f2bf(v.z - bf2f(h2)), l3 = f2bf(v.w - bf2f(h3));
            uint2 ph, pl;
            ph.x = (uint)h0 | ((uint)h1 << 16); ph.y = (uint)h2 | ((uint)h3 << 16);
            pl.x = (uint)l0 | ((uint)l1 << 16); pl.y = (uint)l2 | ((uint)l3 << 16);
            *(uint2*)(Ah + arow * APAD + kk) = ph;
            *(uint2*)(Al + arow * APAD + kk) = pl;
        }
        // ---- stage B transposed (hi/lo), scalar bf16 writes
        #pragma unroll
        for (int half = 0; half < 2; ++half) {
            int kk = bk + half * 16;
            float4 v = *(const float4*)(Wp + (size_t)(k0 + kk) * ldw);
            float vv[4] = {v.x, v.y, v.z, v.w};
            #pragma unroll
            for (int i = 0; i < 4; ++i) {
                ushort h = f2bf(vv[i]);
                ushort l = f2bf(vv[i] - bf2f(h));
                Bh[(bm + i) * BPAD + kk] = h;
                Bl[(bm + i) * BPAD + kk] = l;
            }
        }
        __syncthreads();
        // ---- compute: 4 col-tiles x 3 MFMA
        short8 ah = *(const short8*)aph;
        short8 al = *(const short8*)apl;
        #pragma unroll
        for (int t = 0; t < 4; ++t) {
            const ushort* bp = Bh + (t * 16 + fr) * BPAD + kg * 8;
            const ushort* bq = Bl + (t * 16 + fr) * BPAD + kg * 8;
            short8 bh, bl;
            ((uint2*)&bh)[0] = *(const uint2*)bp;
            ((uint2*)&bh)[1] = *(const uint2*)(bp + 4);
            ((uint2*)&bl)[0] = *(const uint2*)bq;
            ((uint2*)&bl)[1] = *(const uint2*)(bq + 4);
            acc[t] = __builtin_amdgcn_mfma_f32_16x16x32_bf16(ah, bh, acc[t], 0, 0, 0);
            acc[t] = __builtin_amdgcn_mfma_f32_16x16x32_bf16(al, bh, acc[t], 0, 0, 0);
            acc[t] = __builtin_amdgcn_mfma_f32_16x16x32_bf16(ah, bl, acc[t], 0, 0, 0);
        }
        __syncthreads();
    }
    // ---- epilogue: C/D layout col=lane&15, row=(lane>>4)*4+reg
    #pragma unroll
    for (int t = 0; t < 4; ++t) {
        #pragma unroll
        for (int r = 0; r < 4; ++r) {
            int n = n0 + wrow + kg * 4 + r;
            if (n < N) {
                int m = m0 + t * 16 + fr;
                float val = acc[t][r];
                float* cp = C + (size_t)n * ldc + m;
                if (flags & FBIAS) val += bias[m];
                if (flags & FACC)  val += *cp;
                if (flags & FSILU) val = silu_f(val);
                *cp = val;
            }
        }
    }
}

// ---------------------------------------------------------------------------
// s = h @ emb_w + emb_b   (K=5)
// ---------------------------------------------------------------------------
__global__ __launch_bounds__(256) void emb_k(
    const float* __restrict__ h, const float* __restrict__ w,
    const float* __restrict__ b, float* __restrict__ s, int total)
{
    int i = blockIdx.x * 256 + threadIdx.x;
    if (i >= total) return;
    int n = i >> 7, d = i & 127;
    float acc = b[d];
    #pragma unroll
    for (int k = 0; k < 5; ++k) acc = fmaf(h[n * 5 + k], w[k * D + d], acc);
    s[i] = acc;
}

// ---------------------------------------------------------------------------
// Per-edge geometry: unit vector, cosine cutoff, sinc RBF.
// ---------------------------------------------------------------------------
__global__ __launch_bounds__(256) void edge_pre_k(
    const int* __restrict__ ei, const float* __restrict__ pos,
    float* __restrict__ rbf, float* __restrict__ uf, int E)
{
    int e = blockIdx.x * 256 + threadIdx.x;
    if (e >= E) return;
    int r = ei[e], c = ei[E + e];
    float dx = pos[c * 3 + 0] - pos[r * 3 + 0];
    float dy = pos[c * 3 + 1] - pos[r * 3 + 1];
    float dz = pos[c * 3 + 2] - pos[r * 3 + 2];
    float dist = sqrtf(dx * dx + dy * dy + dz * dz);
    float d = fmaxf(dist, 1e-6f);
    float inv = 1.0f / d;
    uf[e * 4 + 0] = dx * inv;
    uf[e * 4 + 1] = dy * inv;
    uf[e * 4 + 2] = dz * inv;
    uf[e * 4 + 3] = (d < CUTOFF) ? 0.5f * (cosf(PI_F * d / CUTOFF) + 1.0f) : 0.0f;
    float w = PI_F * d / CUTOFF;
    #pragma unroll
    for (int k = 1; k <= EDIM; ++k)
        rbf[e * EDIM + (k - 1)] = sinf((float)k * w) * inv;
}

// ---------------------------------------------------------------------------
// CSR construction (in-kernel, once per launch)
// ---------------------------------------------------------------------------
__global__ __launch_bounds__(256) void hist_k(const int* __restrict__ ei,
                                              int* __restrict__ cnt, int E)
{
    int e = blockIdx.x * 256 + threadIdx.x;
    if (e < E) atomicAdd(&cnt[ei[e]], 1);
}

__global__ __launch_bounds__(256) void scan_k(const int* __restrict__ cnt,
                                              int* __restrict__ offs, int n)
{
    __shared__ int tmp[256];
    __shared__ int carry;
    if (threadIdx.x == 0) carry = 0;
    __syncthreads();
    for (int base = 0; base < n; base += 256) {
        int i = base + threadIdx.x;
        int v = (i < n) ? cnt[i] : 0;
        tmp[threadIdx.x] = v;
        __syncthreads();
        for (int off = 1; off < 256; off <<= 1) {
            int add = (threadIdx.x >= off) ? tmp[threadIdx.x - off] : 0;
            __syncthreads();
            tmp[threadIdx.x] += add;
            __syncthreads();
        }
        if (i < n) offs[i + 1] = carry + tmp[threadIdx.x];
        __syncthreads();
        if (threadIdx.x == 255) carry += tmp[255];
        __syncthreads();
    }
    if (threadIdx.x == 0) offs[0] = 0;
}

__global__ __launch_bounds__(256) void initnext_k(const int* __restrict__ offs,
                                                  int* __restrict__ next, int n)
{
    int i = blockIdx.x * 256 + threadIdx.x;
    if (i < n) next[i] = offs[i];
}

__global__ __launch_bounds__(256) void scatter_k(const int* __restrict__ ei,
                                                 int* __restrict__ next,
                                                 int* __restrict__ eid, int E)
{
    int e = blockIdx.x * 256 + threadIdx.x;
    if (e < E) {
        int p = atomicAdd(&next[ei[e]], 1);
        eid[p] = e;
    }
}

// ---------------------------------------------------------------------------
// CSR message pass v2: filter weights in registers (no LDS), 2-edge ILP.
// One node per 128-thread group; register accumulation; one write per node.
// ---------------------------------------------------------------------------
#define MSG_NPB 8
__global__ __launch_bounds__(256) void message_csr_k(
    const int* __restrict__ ei, const int* __restrict__ offs,
    const int* __restrict__ eid,
    const float* __restrict__ rbf, const float* __restrict__ uf,
    const float* __restrict__ P, const float* __restrict__ Vold,
    const float* __restrict__ Wf, const float* __restrict__ bf,
    float* __restrict__ S, float* __restrict__ Vnew, int N, int E)
{
    const int sub = threadIdx.x >> 7;
    const int d = threadIdx.x & 127;
    float ws[EDIM], wvv[EDIM], wvw[EDIM];
    #pragma unroll
    for (int k = 0; k < EDIM; ++k) {
        ws[k]  = Wf[k * D3 + d];
        wvv[k] = Wf[k * D3 + D + d];
        wvw[k] = Wf[k * D3 + 2 * D + d];
    }
    const float bs = bf[d], bvv = bf[D + d], bvw = bf[2 * D + d];

    auto edge = [&](int e, float& ds, float& dvx, float& dvy, float& dvz) {
        float4 u4 = *(const float4*)(uf + (size_t)e * 4);
        int col = ei[E + e];
        const float* rb = rbf + (size_t)e * EDIM;
        float4 r0 = *(const float4*)(rb);
        float4 r1 = *(const float4*)(rb + 4);
        float4 r2 = *(const float4*)(rb + 8);
        float4 r3 = *(const float4*)(rb + 12);
        float4 r4 = *(const float4*)(rb + 16);
        float rv[EDIM] = {r0.x, r0.y, r0.z, r0.w, r1.x, r1.y, r1.z, r1.w,
                          r2.x, r2.y, r2.z, r2.w, r3.x, r3.y, r3.z, r3.w,
                          r4.x, r4.y, r4.z, r4.w};
        float fs = bs, fvv = bvv, fvw = bvw;
        #pragma unroll
        for (int k = 0; k < EDIM; ++k) {
            fs  = fmaf(rv[k], ws[k], fs);
            fvv = fmaf(rv[k], wvv[k], fvv);
            fvw = fmaf(rv[k], wvw[k], fvw);
        }
        float fc = u4.w;
        const float* pc = P + (size_t)col * D3;
        const float* vc = Vold + (size_t)col * D3;
        float xs  = pc[d] * fs * fc;
        float xvv = pc[D + d] * fvv * fc;
        float xvw = pc[2 * D + d] * fvw * fc;
        ds += xs;
        dvx = fmaf(xvv, vc[d],         fmaf(xvw, u4.x, dvx));
        dvy = fmaf(xvv, vc[D + d],     fmaf(xvw, u4.y, dvy));
        dvz = fmaf(xvv, vc[2 * D + d], fmaf(xvw, u4.z, dvz));
    };

    for (int it = 0; it < MSG_NPB / 2; ++it) {
        int n = blockIdx.x * MSG_NPB + it * 2 + sub;
        if (n >= N) return;   // no __syncthreads in kernel: safe
        float ds0 = 0.f, dx0 = 0.f, dy0 = 0.f, dz0 = 0.f;
        float ds1 = 0.f, dx1 = 0.f, dy1 = 0.f, dz1 = 0.f;
        const int j0 = offs[n], j1 = offs[n + 1];
        int j = j0;
        for (; j + 2 <= j1; j += 2) {
            int e0 = eid[j], e1 = eid[j + 1];
            edge(e0, ds0, dx0, dy0, dz0);
            edge(e1, ds1, dx1, dy1, dz1);
        }
        if (j < j1) edge(eid[j], ds0, dx0, dy0, dz0);
        S[(size_t)n * D + d] += ds0 + ds1;
        const float* vo = Vold + (size_t)n * D3;
        float* vn = Vnew + (size_t)n * D3;
        vn[d]         = vo[d] + dx0 + dx1;
        vn[D + d]     = vo[D + d] + dy0 + dy1;
        vn[2 * D + d] = vo[2 * D + d] + dz0 + dz1;
    }
}

// Vn[n,d] = sqrt(sum_c V3[n,c,d]^2 + 1e-8)
__global__ __launch_bounds__(256) void norm3_k(const float* __restrict__ V3,
                                               float* __restrict__ Vn, int total)
{
    int i = blockIdx.x * 256 + threadIdx.x;
    if (i >= total) return;
    int n = i >> 7, d = i & 127;
    const float* b = V3 + (size_t)n * D3;
    float x = b[d], y = b[D + d], z = b[2 * D + d];
    Vn[i] = sqrtf(fmaf(x, x, fmaf(y, y, fmaf(z, z, 1e-8f))));
}

// s += a_ss + a_sv * <Uv,Vv>;  v += a_vv * Uv
__global__ __launch_bounds__(256) void upd_apply_k(
    const float* __restrict__ U3, const float* __restrict__ V3,
    const float* __restrict__ P, float* __restrict__ s,
    float* __restrict__ v, int total)
{
    int i = blockIdx.x * 256 + threadIdx.x;
    if (i >= total) return;
    int n = i >> 7, d = i & 127;
    const float* u = U3 + (size_t)n * D3;
    const float* w = V3 + (size_t)n * D3;
    float ux = u[d], uy = u[D + d], uz = u[2 * D + d];
    float vx = w[d], vy = w[D + d], vz = w[2 * D + d];
    float dot = fmaf(ux, vx, fmaf(uy, vy, uz * vz));
    const float* a = P + (size_t)n * D3;
    s[i] += a[d] + a[D + d] * dot;
    float avv = a[2 * D + d];
    float* vv = v + (size_t)n * D3;
    vv[d]         = fmaf(avv, ux, vv[d]);
    vv[D + d]     = fmaf(avv, uy, vv[D + d]);
    vv[2 * D + d] = fmaf(avv, uz, vv[2 * D + d]);
}

// s = a[:, :D];  v = a[:, D:2D, None] * v1
__global__ __launch_bounds__(256) void geb_apply_k(
    const float* __restrict__ P, const float* __restrict__ U3,
    float* __restrict__ s, float* __restrict__ v, int total)
{
    int i = blockIdx.x * 256 + threadIdx.x;
    if (i >= total) return;
    int n = i >> 7, d = i & 127;
    const float* a = P + (size_t)n * 2 * D;
    s[i] = a[d];
    float g = a[D + d];
    const float* u = U3 + (size_t)n * D3;
    float* vv = v + (size_t)n * D3;
    vv[d]         = g * u[d];
    vv[D + d]     = g * u[D + d];
    vv[2 * D + d] = g * u[2 * D + d];
}

// out[batch[n]] += hidden[n] @ ro_w2 + ro_b2
__global__ __launch_bounds__(256) void readout_k(
    const float* __restrict__ H2, const float* __restrict__ w2,
    const float* __restrict__ b2, const int* __restrict__ batch,
    float* __restrict__ out, int N)
{
    int n = blockIdx.x * 256 + threadIdx.x;
    if (n >= N) return;
    float acc = b2[0];
    const float* hrow = H2 + (size_t)n * HROH;
    #pragma unroll
    for (int k = 0; k < HROH; ++k) acc = fmaf(hrow[k], w2[k], acc);
    atomicAdd(out + batch[n], acc);
}

// ---------------------------------------------------------------------------

static inline void gemm(hipStream_t st, const float* A, int lda, int zsA,
                        const float* W, int ldw, const float* bias,
                        float* C, int ldc, int zsC,
                        int N, int K, int M, int flags, int Z = 1)
{
    dim3 g((N + TLR - 1) / TLR, M / TLC, Z);
    hipLaunchKernelGGL(gemm_k, g, dim3(256), 0, st,
                       A, lda, zsA, W, ldw, bias, C, ldc, zsC, N, K, flags);
}

extern "C" void kernel_launch(void* const* d_in, const int* in_sizes, int n_in,
                              void* d_out, int out_size, void* d_ws, size_t ws_size,
                              hipStream_t stream)
{
    const float* h          = (const float*)d_in[0];
    const float* pos        = (const float*)d_in[1];
    const int*   ei         = (const int*)d_in[2];
    const int*   batch      = (const int*)d_in[3];
    const float* emb_w      = (const float*)d_in[4];
    const float* emb_b      = (const float*)d_in[5];
    const float* msg_phi_w1 = (const float*)d_in[6];
    const float* msg_phi_b1 = (const float*)d_in[7];
    const float* msg_phi_w2 = (const float*)d_in[8];
    const float* msg_phi_b2 = (const float*)d_in[9];
    const float* msg_filt_w = (const float*)d_in[10];
    const float* msg_filt_b = (const float*)d_in[11];
    const float* upd_U      = (const float*)d_in[12];
    const float* upd_V      = (const float*)d_in[13];
    const float* upd_w1     = (const float*)d_in[14];
    const float* upd_b1     = (const float*)d_in[15];
    const float* upd_w2     = (const float*)d_in[16];
    const float* upd_b2     = (const float*)d_in[17];
    const float* geb_wv1    = (const float*)d_in[18];
    const float* geb_wv2    = (const float*)d_in[19];
    const float* geb_w1     = (const float*)d_in[20];
    const float* geb_b1     = (const float*)d_in[21];
    const float* geb_w2     = (const float*)d_in[22];
    const float* geb_b2     = (const float*)d_in[23];
    const float* ro_w1      = (const float*)d_in[24];
    const float* ro_b1      = (const float*)d_in[25];
    const float* ro_w2      = (const float*)d_in[26];
    const float* ro_b2      = (const float*)d_in[27];
    float* out = (float*)d_out;

    const int N = NNODES, E = NEDGES;

    char* p = (char*)d_ws;
    auto carve = [&](size_t bytes) {
        char* r = p;
        p += (bytes + 255) & ~(size_t)255;
        return r;
    };
    float* S    = (float*)carve((size_t)N * D * 4);
    float* VA   = (float*)carve((size_t)N * D3 * 4);
    float* VB   = (float*)carve((size_t)N * D3 * 4);
    float* P_   = (float*)carve((size_t)N * D3 * 4);
    float* H    = (float*)carve((size_t)N * D * 4);
    float* H2   = (float*)carve((size_t)N * D * 4);
    float* V3   = (float*)carve((size_t)N * D3 * 4);
    float* RBF  = (float*)carve((size_t)E * EDIM * 4);
    float* UF   = (float*)carve((size_t)E * 4 * 4);
    int*   offs = (int*)carve((size_t)(N + 1) * 4);
    int*   nxt  = (int*)carve((size_t)N * 4);
    int*   eidb = (int*)carve((size_t)E * 4);

    // init: s = emb(h), v = 0, edge geometry, CSR
    hipMemsetAsync(VA, 0, (size_t)N * D3 * 4, stream);
    hipLaunchKernelGGL(emb_k, dim3((N * D + 255) / 256), dim3(256), 0, stream,
                       h, emb_w, emb_b, S, N * D);
    hipLaunchKernelGGL(edge_pre_k, dim3((E + 255) / 256), dim3(256), 0, stream,
                       ei, pos, RBF, UF, E);
    hipMemsetAsync(nxt, 0, (size_t)N * 4, stream);
    hipLaunchKernelGGL(hist_k, dim3((E + 255) / 256), dim3(256), 0, stream, ei, nxt, E);
    hipLaunchKernelGGL(scan_k, dim3(1), dim3(256), 0, stream, nxt, offs, N);
    hipLaunchKernelGGL(initnext_k, dim3((N + 255) / 256), dim3(256), 0, stream,
                       offs, nxt, N);
    hipLaunchKernelGGL(scatter_k, dim3((E + 255) / 256), dim3(256), 0, stream,
                       ei, nxt, eidb, E);

    float* Vc = VA;   // current v state
    float* Vs = VB;   // spare (message target / dead-buffer scratch)

    for (int r = 0; r < NR; ++r) {
        // phi = silu(s@W1+b1)@W2+b2
        gemm(stream, S, D, 0, msg_phi_w1 + (size_t)r * D * D, D,
             msg_phi_b1 + (size_t)r * D, H, D, 0, N, D, D, FBIAS | FSILU);
        gemm(stream, H, D, 0, msg_phi_w2 + (size_t)r * D * D3, D3,
             msg_phi_b2 + (size_t)r * D3, P_, D3, 0, N, D, D3, FBIAS);
        // message: read Vc, write Vs (= Vc + dv); S += ds
        hipLaunchKernelGGL(message_csr_k, dim3((N + MSG_NPB - 1) / MSG_NPB),
                           dim3(256), 0, stream,
                           ei, offs, eidb, RBF, UF, P_, Vc,
                           msg_filt_w + (size_t)r * EDIM * D3,
                           msg_filt_b + (size_t)r * D3, S, Vs, N, E);
        { float* t = Vc; Vc = Vs; Vs = t; }   // Vc = new state, Vs = dead
        float* Uv = Vs;                       // reuse dead buffer for Uv
        // update
        gemm(stream, Vc, D3, D, upd_U + (size_t)r * D * D, D, nullptr,
             Uv, D3, D, N, D, D, 0, 3);
        gemm(stream, Vc, D3, D, upd_V + (size_t)r * D * D, D, nullptr,
             V3, D3, D, N, D, D, 0, 3);
        hipLaunchKernelGGL(norm3_k, dim3((N * D + 255) / 256), dim3(256), 0, stream,
                           V3, H, N * D);
        gemm(stream, S, D, 0, upd_w1 + (size_t)r * 2 * D * D, D,
             upd_b1 + (size_t)r * D, H2, D, 0, N, D, D, FBIAS);
        gemm(stream, H, D, 0, upd_w1 + (size_t)r * 2 * D * D + D * D, D,
             nullptr, H2, D, 0, N, D, D, FACC | FSILU);
        gemm(stream, H2, D, 0, upd_w2 + (size_t)r * D * D3, D3,
             upd_b2 + (size_t)r * D3, P_, D3, 0, N, D, D3, FBIAS);
        hipLaunchKernelGGL(upd_apply_k, dim3((N * D + 255) / 256), dim3(256), 0, stream,
                           Uv, V3, P_, S, Vc, N * D);
    }

    for (int g = 0; g < NG; ++g) {
        float* Uv = Vs;   // dead buffer as v1 scratch
        gemm(stream, Vc, D3, D, geb_wv1 + (size_t)g * D * D, D, nullptr,
             Uv, D3, D, N, D, D, 0, 3);
        gemm(stream, Vc, D3, D, geb_wv2 + (size_t)g * D * D, D, nullptr,
             V3, D3, D, N, D, D, 0, 3);
        hipLaunchKernelGGL(norm3_k, dim3((N * D + 255) / 256), dim3(256), 0, stream,
                           V3, H, N * D);
        gemm(stream, S, D, 0, geb_w1 + (size_t)g * 2 * D * D, D,
             geb_b1 + (size_t)g * D, H2, D, 0, N, D, D, FBIAS);
        gemm(stream, H, D, 0, geb_w1 + (size_t)g * 2 * D * D + D * D, D,
             nullptr, H2, D, 0, N, D, D, FACC | FSILU);
        gemm(stream, H2, D, 0, geb_w2 + (size_t)g * D * 2 * D, 2 * D,
             geb_b2 + (size_t)g * 2 * D, P_, 2 * D, 0, N, D, 2 * D, FBIAS);
        hipLaunchKernelGGL(geb_apply_k, dim3((N * D + 255) / 256), dim3(256), 0, stream,
                           P_, Uv, S, Vc, N * D);
    }

    // readout
    gemm(stream, S, D, 0, ro_w1, HROH, ro_b1, H2, HROH, 0, N, D, HROH, FBIAS | FSILU);
    hipMemsetAsync(out, 0, (size_t)NMOL * 4, stream);
    hipLaunchKernelGGL(readout_k, dim3((N + 255) / 256), dim3(256), 0, stream,
                       H2, ro_w2, ro_b2, batch, out, N);
}

// Round 4
// 979.727 us; speedup vs baseline: 1.7607x; 1.2113x over previous
//
#include <hip/hip_runtime.h>

typedef __attribute__((ext_vector_type(4))) float f32x4;
typedef __attribute__((ext_vector_type(8))) short short8;

#define D 128
#define D3 384
#define SLD 256   // S buffer row stride: [s | Vn]
#define EDIM 20
#define NR 3
#define NG 3
#define CUTOFF 5.0f
#define NNODES 10000
#define NEDGES 160000
#define NMOL 500
#define HROH 64
#define PI_F 3.14159265358979323846f

#define FBIAS 1
#define FSILU 2

static __device__ __forceinline__ float silu_f(float x) {
    return x / (1.0f + expf(-x));
}

// bf16 split helpers (round-to-nearest-even)
static __device__ __forceinline__ ushort f2bf(float x) {
    uint u = __float_as_uint(x);
    uint r = (u + 0x7fffu + ((u >> 16) & 1u)) >> 16;
    return (ushort)r;
}
static __device__ __forceinline__ float bf2f(ushort h) {
    return __uint_as_float((uint)h << 16);
}

// ---------------------------------------------------------------------------
// MFMA bf16x3 GEMM: C[n,m] = act(A[n,:] @ W[:,m] + bias[m])
// f32 inputs split to hi/lo bf16 in staging; acc = ah*bh + al*bh + ah*bl.
// Tile 64x64, 256 threads (4 waves x 16 rows), K-chunk 32, K mult of 32.
// TWO=true: grid.z = 6 -> (coord = z>>1, sel = z&1) picks (WA,CA)/(WB,CB):
// fuses the upd_U/upd_V (and geb wv1/wv2) pair into one dispatch.
// ---------------------------------------------------------------------------
#define TLR 64
#define TLC 64
#define KC 32
#define APAD 40
#define BPAD 36

template <bool TWO>
__global__ __launch_bounds__(256) void gemm_t(
    const float* __restrict__ A, int lda, int zsA,
    const float* __restrict__ WA, const float* __restrict__ WB, int ldw,
    const float* __restrict__ bias,
    float* __restrict__ CA, float* __restrict__ CB, int ldc, int zsC,
    int N, int K, int flags)
{
    int coord, sel;
    if (TWO) { coord = blockIdx.z >> 1; sel = blockIdx.z & 1; }
    else     { coord = blockIdx.z;      sel = 0; }
    const float* W = (TWO && sel) ? WB : WA;
    float* C = ((TWO && sel) ? CB : CA) + (size_t)coord * zsC;
    A += (size_t)coord * zsA;

    const int n0 = blockIdx.x * TLR;
    const int m0 = blockIdx.y * TLC;
    __shared__ ushort Ah[TLR * APAD], Al[TLR * APAD];
    __shared__ ushort Bh[TLC * BPAD], Bl[TLC * BPAD];   // transposed: [col][k]
    const int tid = threadIdx.x;
    const int arow = tid & 63;
    const int akq = (tid >> 6) * 4;
    const bool aok = (n0 + arow) < N;
    const float* Ar = A + (size_t)(n0 + arow) * lda;
    const int bk = tid >> 4;
    const int bm = (tid & 15) * 4;
    const float* Wp = W + m0 + bm;
    const int lane = tid & 63;
    const int wrow = (tid >> 6) * 16;
    const int fr = lane & 15;
    const int kg = lane >> 4;
    const ushort* aph = Ah + (wrow + fr) * APAD + kg * 8;
    const ushort* apl = Al + (wrow + fr) * APAD + kg * 8;

    f32x4 acc[4];
    #pragma unroll
    for (int t = 0; t < 4; ++t) acc[t] = (f32x4){0.f, 0.f, 0.f, 0.f};

    for (int k0 = 0; k0 < K; k0 += KC) {
        #pragma unroll
        for (int half = 0; half < 2; ++half) {
            int kk = akq + half * 16;
            float4 v = aok ? *(const float4*)(Ar + k0 + kk)
                           : make_float4(0.f, 0.f, 0.f, 0.f);
            ushort h0 = f2bf(v.x), h1 = f2bf(v.y), h2 = f2bf(v.z), h3 = f2bf(v.w);
            ushort l0 = f2bf(v.x - bf2f(h0)), l1 = f2bf(v.y - bf2f(h1));
            ushort l2 = f2bf(v.z - bf2f(h2)), l3 = f2bf(v.w - bf2f(h3));
            uint2 ph, pl;
            ph.x = (uint)h0 | ((uint)h1 << 16); ph.y = (uint)h2 | ((uint)h3 << 16);
            pl.x = (uint)l0 | ((uint)l1 << 16); pl.y = (uint)l2 | ((uint)l3 << 16);
            *(uint2*)(Ah + arow * APAD + kk) = ph;
            *(uint2*)(Al + arow * APAD + kk) = pl;
        }
        #pragma unroll
        for (int half = 0; half < 2; ++half) {
            int kk = bk + half * 16;
            float4 v = *(const float4*)(Wp + (size_t)(k0 + kk) * ldw);
            float vv[4] = {v.x, v.y, v.z, v.w};
            #pragma unroll
            for (int i = 0; i < 4; ++i) {
                ushort hh = f2bf(vv[i]);
                ushort ll = f2bf(vv[i] - bf2f(hh));
                Bh[(bm + i) * BPAD + kk] = hh;
                Bl[(bm + i) * BPAD + kk] = ll;
            }
        }
        __syncthreads();
        short8 ah = *(const short8*)aph;
        short8 al = *(const short8*)apl;
        #pragma unroll
        for (int t = 0; t < 4; ++t) {
            const ushort* bp = Bh + (t * 16 + fr) * BPAD + kg * 8;
            const ushort* bq = Bl + (t * 16 + fr) * BPAD + kg * 8;
            short8 bh, bl;
            ((uint2*)&bh)[0] = *(const uint2*)bp;
            ((uint2*)&bh)[1] = *(const uint2*)(bp + 4);
            ((uint2*)&bl)[0] = *(const uint2*)bq;
            ((uint2*)&bl)[1] = *(const uint2*)(bq + 4);
            acc[t] = __builtin_amdgcn_mfma_f32_16x16x32_bf16(ah, bh, acc[t], 0, 0, 0);
            acc[t] = __builtin_amdgcn_mfma_f32_16x16x32_bf16(al, bh, acc[t], 0, 0, 0);
            acc[t] = __builtin_amdgcn_mfma_f32_16x16x32_bf16(ah, bl, acc[t], 0, 0, 0);
        }
        __syncthreads();
    }
    #pragma unroll
    for (int t = 0; t < 4; ++t) {
        #pragma unroll
        for (int r = 0; r < 4; ++r) {
            int n = n0 + wrow + kg * 4 + r;
            if (n < N) {
                int m = m0 + t * 16 + fr;
                float val = acc[t][r];
                float* cp = C + (size_t)n * ldc + m;
                if (flags & FBIAS) val += bias[m];
                if (flags & FSILU) val = silu_f(val);
                *cp = val;
            }
        }
    }
}

// ---------------------------------------------------------------------------
// s = h @ emb_w + emb_b   (K=5); S has row stride SLD
// ---------------------------------------------------------------------------
__global__ __launch_bounds__(256) void emb_k(
    const float* __restrict__ h, const float* __restrict__ w,
    const float* __restrict__ b, float* __restrict__ s, int total)
{
    int i = blockIdx.x * 256 + threadIdx.x;
    if (i >= total) return;
    int n = i >> 7, d = i & 127;
    float acc = b[d];
    #pragma unroll
    for (int k = 0; k < 5; ++k) acc = fmaf(h[n * 5 + k], w[k * D + d], acc);
    s[(size_t)n * SLD + d] = acc;
}

// ---------------------------------------------------------------------------
// CSR construction
// ---------------------------------------------------------------------------
__global__ __launch_bounds__(256) void hist_k(const int* __restrict__ ei,
                                              int* __restrict__ cnt, int E)
{
    int e = blockIdx.x * 256 + threadIdx.x;
    if (e < E) atomicAdd(&cnt[ei[e]], 1);
}

__global__ __launch_bounds__(256) void scan_k(const int* __restrict__ cnt,
                                              int* __restrict__ offs, int n)
{
    __shared__ int tmp[256];
    __shared__ int carry;
    if (threadIdx.x == 0) carry = 0;
    __syncthreads();
    for (int base = 0; base < n; base += 256) {
        int i = base + threadIdx.x;
        int v = (i < n) ? cnt[i] : 0;
        tmp[threadIdx.x] = v;
        __syncthreads();
        for (int off = 1; off < 256; off <<= 1) {
            int add = (threadIdx.x >= off) ? tmp[threadIdx.x - off] : 0;
            __syncthreads();
            tmp[threadIdx.x] += add;
            __syncthreads();
        }
        if (i < n) offs[i + 1] = carry + tmp[threadIdx.x];
        __syncthreads();
        if (threadIdx.x == 255) carry += tmp[255];
        __syncthreads();
    }
    if (threadIdx.x == 0) offs[0] = 0;
}

__global__ __launch_bounds__(256) void initnext_k(const int* __restrict__ offs,
                                                  int* __restrict__ next, int n)
{
    int i = blockIdx.x * 256 + threadIdx.x;
    if (i < n) next[i] = offs[i];
}

// ---------------------------------------------------------------------------
// Edge geometry, written directly into CSR-sorted slots: message-pass reads
// col_s/uf_s/rbf_s sequentially (no eid indirection, coalesced edge data).
// ---------------------------------------------------------------------------
__global__ __launch_bounds__(256) void edge_pre_k(
    const int* __restrict__ ei, const float* __restrict__ pos,
    int* __restrict__ next, float* __restrict__ rbf_s,
    float* __restrict__ uf_s, int* __restrict__ col_s, int E)
{
    int e = blockIdx.x * 256 + threadIdx.x;
    if (e >= E) return;
    int r = ei[e], c = ei[E + e];
    float dx = pos[c * 3 + 0] - pos[r * 3 + 0];
    float dy = pos[c * 3 + 1] - pos[r * 3 + 1];
    float dz = pos[c * 3 + 2] - pos[r * 3 + 2];
    float dist = sqrtf(dx * dx + dy * dy + dz * dz);
    float d = fmaxf(dist, 1e-6f);
    float inv = 1.0f / d;
    int p = atomicAdd(&next[r], 1);
    col_s[p] = c;
    uf_s[p * 4 + 0] = dx * inv;
    uf_s[p * 4 + 1] = dy * inv;
    uf_s[p * 4 + 2] = dz * inv;
    uf_s[p * 4 + 3] = (d < CUTOFF) ? 0.5f * (cosf(PI_F * d / CUTOFF) + 1.0f) : 0.0f;
    float w = PI_F * d / CUTOFF;
    #pragma unroll
    for (int k = 1; k <= EDIM; ++k)
        rbf_s[(size_t)p * EDIM + (k - 1)] = sinf((float)k * w) * inv;
}

// ---------------------------------------------------------------------------
// CSR message pass v3: sequential edge arrays, register filter weights,
// 2-edge ILP, register accumulation, one write per node.
// ---------------------------------------------------------------------------
#define MSG_NPB 4
__global__ __launch_bounds__(256) void message_csr_k(
    const int* __restrict__ offs, const int* __restrict__ col_s,
    const float* __restrict__ rbf_s, const float* __restrict__ uf_s,
    const float* __restrict__ P, const float* __restrict__ Vold,
    const float* __restrict__ Wf, const float* __restrict__ bf,
    float* __restrict__ S, float* __restrict__ Vnew, int N)
{
    const int sub = threadIdx.x >> 7;
    const int d = threadIdx.x & 127;
    float ws[EDIM], wvv[EDIM], wvw[EDIM];
    #pragma unroll
    for (int k = 0; k < EDIM; ++k) {
        ws[k]  = Wf[k * D3 + d];
        wvv[k] = Wf[k * D3 + D + d];
        wvw[k] = Wf[k * D3 + 2 * D + d];
    }
    const float bs = bf[d], bvv = bf[D + d], bvw = bf[2 * D + d];

    auto edge = [&](int j, float& ds, float& dvx, float& dvy, float& dvz) {
        float4 u4 = *(const float4*)(uf_s + (size_t)j * 4);
        int col = col_s[j];
        const float* rb = rbf_s + (size_t)j * EDIM;
        float4 r0 = *(const float4*)(rb);
        float4 r1 = *(const float4*)(rb + 4);
        float4 r2 = *(const float4*)(rb + 8);
        float4 r3 = *(const float4*)(rb + 12);
        float4 r4 = *(const float4*)(rb + 16);
        float rv[EDIM] = {r0.x, r0.y, r0.z, r0.w, r1.x, r1.y, r1.z, r1.w,
                          r2.x, r2.y, r2.z, r2.w, r3.x, r3.y, r3.z, r3.w,
                          r4.x, r4.y, r4.z, r4.w};
        float fs = bs, fvv = bvv, fvw = bvw;
        #pragma unroll
        for (int k = 0; k < EDIM; ++k) {
            fs  = fmaf(rv[k], ws[k], fs);
            fvv = fmaf(rv[k], wvv[k], fvv);
            fvw = fmaf(rv[k], wvw[k], fvw);
        }
        float fc = u4.w;
        const float* pc = P + (size_t)col * D3;
        const float* vc = Vold + (size_t)col * D3;
        float xs  = pc[d] * fs * fc;
        float xvv = pc[D + d] * fvv * fc;
        float xvw = pc[2 * D + d] * fvw * fc;
        ds += xs;
        dvx = fmaf(xvv, vc[d],         fmaf(xvw, u4.x, dvx));
        dvy = fmaf(xvv, vc[D + d],     fmaf(xvw, u4.y, dvy));
        dvz = fmaf(xvv, vc[2 * D + d], fmaf(xvw, u4.z, dvz));
    };

    for (int it = 0; it < MSG_NPB / 2; ++it) {
        int n = blockIdx.x * MSG_NPB + it * 2 + sub;
        if (n >= N) return;   // no __syncthreads in kernel: safe
        float ds0 = 0.f, dx0 = 0.f, dy0 = 0.f, dz0 = 0.f;
        float ds1 = 0.f, dx1 = 0.f, dy1 = 0.f, dz1 = 0.f;
        const int j0 = offs[n], j1 = offs[n + 1];
        int j = j0;
        for (; j + 2 <= j1; j += 2) {
            edge(j, ds0, dx0, dy0, dz0);
            edge(j + 1, ds1, dx1, dy1, dz1);
        }
        if (j < j1) edge(j, ds0, dx0, dy0, dz0);
        S[(size_t)n * SLD + d] += ds0 + ds1;
        const float* vo = Vold + (size_t)n * D3;
        float* vn = Vnew + (size_t)n * D3;
        vn[d]         = vo[d] + dx0 + dx1;
        vn[D + d]     = vo[D + d] + dy0 + dy1;
        vn[2 * D + d] = vo[2 * D + d] + dz0 + dz1;
    }
}

// Vn -> SX[:,128:256]:  SX[n*SLD + 128 + d] = sqrt(sum_c V3[n,c,d]^2 + 1e-8)
__global__ __launch_bounds__(256) void norm3_k(const float* __restrict__ V3,
                                               float* __restrict__ SX, int total)
{
    int i = blockIdx.x * 256 + threadIdx.x;
    if (i >= total) return;
    int n = i >> 7, d = i & 127;
    const float* b = V3 + (size_t)n * D3;
    float x = b[d], y = b[D + d], z = b[2 * D + d];
    SX[(size_t)n * SLD + D + d] = sqrtf(fmaf(x, x, fmaf(y, y, fmaf(z, z, 1e-8f))));
}

// s += a_ss + a_sv * <Uv,Vv>;  v += a_vv * Uv
__global__ __launch_bounds__(256) void upd_apply_k(
    const float* __restrict__ U3, const float* __restrict__ V3,
    const float* __restrict__ P, float* __restrict__ s,
    float* __restrict__ v, int total)
{
    int i = blockIdx.x * 256 + threadIdx.x;
    if (i >= total) return;
    int n = i >> 7, d = i & 127;
    const float* u = U3 + (size_t)n * D3;
    const float* w = V3 + (size_t)n * D3;
    float ux = u[d], uy = u[D + d], uz = u[2 * D + d];
    float vx = w[d], vy = w[D + d], vz = w[2 * D + d];
    float dot = fmaf(ux, vx, fmaf(uy, vy, uz * vz));
    const float* a = P + (size_t)n * D3;
    s[(size_t)n * SLD + d] += a[d] + a[D + d] * dot;
    float avv = a[2 * D + d];
    float* vv = v + (size_t)n * D3;
    vv[d]         = fmaf(avv, ux, vv[d]);
    vv[D + d]     = fmaf(avv, uy, vv[D + d]);
    vv[2 * D + d] = fmaf(avv, uz, vv[2 * D + d]);
}

// s = a[:, :D];  v = a[:, D:2D, None] * v1
__global__ __launch_bounds__(256) void geb_apply_k(
    const float* __restrict__ P, const float* __restrict__ U3,
    float* __restrict__ s, float* __restrict__ v, int total)
{
    int i = blockIdx.x * 256 + threadIdx.x;
    if (i >= total) return;
    int n = i >> 7, d = i & 127;
    const float* a = P + (size_t)n * 2 * D;
    s[(size_t)n * SLD + d] = a[d];
    float g = a[D + d];
    const float* u = U3 + (size_t)n * D3;
    float* vv = v + (size_t)n * D3;
    vv[d]         = g * u[d];
    vv[D + d]     = g * u[D + d];
    vv[2 * D + d] = g * u[2 * D + d];
}

// out[batch[n]] += hidden[n] @ ro_w2 + ro_b2
__global__ __launch_bounds__(256) void readout_k(
    const float* __restrict__ H2, const float* __restrict__ w2,
    const float* __restrict__ b2, const int* __restrict__ batch,
    float* __restrict__ out, int N)
{
    int n = blockIdx.x * 256 + threadIdx.x;
    if (n >= N) return;
    float acc = b2[0];
    const float* hrow = H2 + (size_t)n * HROH;
    #pragma unroll
    for (int k = 0; k < HROH; ++k) acc = fmaf(hrow[k], w2[k], acc);
    atomicAdd(out + batch[n], acc);
}

// ---------------------------------------------------------------------------

static inline void gemm(hipStream_t st, const float* A, int lda, int zsA,
                        const float* W, int ldw, const float* bias,
                        float* C, int ldc, int zsC,
                        int N, int K, int M, int flags, int Z = 1)
{
    dim3 g((N + TLR - 1) / TLR, M / TLC, Z);
    hipLaunchKernelGGL(HIP_KERNEL_NAME(gemm_t<false>), g, dim3(256), 0, st,
                       A, lda, zsA, W, nullptr, ldw, bias, C, nullptr, ldc, zsC,
                       N, K, flags);
}

static inline void gemm2(hipStream_t st, const float* A, int lda, int zsA,
                         const float* WA, const float* WB, int ldw,
                         float* CA, float* CB, int ldc, int zsC,
                         int N, int K, int M)
{
    dim3 g((N + TLR - 1) / TLR, M / TLC, 6);
    hipLaunchKernelGGL(HIP_KERNEL_NAME(gemm_t<true>), g, dim3(256), 0, st,
                       A, lda, zsA, WA, WB, ldw, nullptr, CA, CB, ldc, zsC,
                       N, K, 0);
}

extern "C" void kernel_launch(void* const* d_in, const int* in_sizes, int n_in,
                              void* d_out, int out_size, void* d_ws, size_t ws_size,
                              hipStream_t stream)
{
    const float* h          = (const float*)d_in[0];
    const float* pos        = (const float*)d_in[1];
    const int*   ei         = (const int*)d_in[2];
    const int*   batch      = (const int*)d_in[3];
    const float* emb_w      = (const float*)d_in[4];
    const float* emb_b      = (const float*)d_in[5];
    const float* msg_phi_w1 = (const float*)d_in[6];
    const float* msg_phi_b1 = (const float*)d_in[7];
    const float* msg_phi_w2 = (const float*)d_in[8];
    const float* msg_phi_b2 = (const float*)d_in[9];
    const float* msg_filt_w = (const float*)d_in[10];
    const float* msg_filt_b = (const float*)d_in[11];
    const float* upd_U      = (const float*)d_in[12];
    const float* upd_V      = (const float*)d_in[13];
    const float* upd_w1     = (const float*)d_in[14];
    const float* upd_b1     = (const float*)d_in[15];
    const float* upd_w2     = (const float*)d_in[16];
    const float* upd_b2     = (const float*)d_in[17];
    const float* geb_wv1    = (const float*)d_in[18];
    const float* geb_wv2    = (const float*)d_in[19];
    const float* geb_w1     = (const float*)d_in[20];
    const float* geb_b1     = (const float*)d_in[21];
    const float* geb_w2     = (const float*)d_in[22];
    const float* geb_b2     = (const float*)d_in[23];
    const float* ro_w1      = (const float*)d_in[24];
    const float* ro_b1      = (const float*)d_in[25];
    const float* ro_w2      = (const float*)d_in[26];
    const float* ro_b2      = (const float*)d_in[27];
    float* out = (float*)d_out;

    const int N = NNODES, E = NEDGES;

    char* p = (char*)d_ws;
    auto carve = [&](size_t bytes) {
        char* r = p;
        p += (bytes + 255) & ~(size_t)255;
        return r;
    };
    float* SX   = (float*)carve((size_t)N * SLD * 4);   // [s | Vn]
    float* VA   = (float*)carve((size_t)N * D3 * 4);
    float* VB   = (float*)carve((size_t)N * D3 * 4);
    float* P_   = (float*)carve((size_t)N * D3 * 4);
    float* H    = (float*)carve((size_t)N * D * 4);
    float* H2   = (float*)carve((size_t)N * D * 4);
    float* V3   = (float*)carve((size_t)N * D3 * 4);
    float* RBFs = (float*)carve((size_t)E * EDIM * 4);
    float* UFs  = (float*)carve((size_t)E * 4 * 4);
    int*   COLs = (int*)carve((size_t)E * 4);
    int*   offs = (int*)carve((size_t)(N + 1) * 4);
    int*   nxt  = (int*)carve((size_t)N * 4);

    // init: s = emb(h), v = 0, CSR offsets, sorted edge geometry
    hipMemsetAsync(VA, 0, (size_t)N * D3 * 4, stream);
    hipLaunchKernelGGL(emb_k, dim3((N * D + 255) / 256), dim3(256), 0, stream,
                       h, emb_w, emb_b, SX, N * D);
    hipMemsetAsync(nxt, 0, (size_t)N * 4, stream);
    hipLaunchKernelGGL(hist_k, dim3((E + 255) / 256), dim3(256), 0, stream, ei, nxt, E);
    hipLaunchKernelGGL(scan_k, dim3(1), dim3(256), 0, stream, nxt, offs, N);
    hipLaunchKernelGGL(initnext_k, dim3((N + 255) / 256), dim3(256), 0, stream,
                       offs, nxt, N);
    hipLaunchKernelGGL(edge_pre_k, dim3((E + 255) / 256), dim3(256), 0, stream,
                       ei, pos, nxt, RBFs, UFs, COLs, E);

    float* Vc = VA;
    float* Vs = VB;

    for (int r = 0; r < NR; ++r) {
        // phi = silu(s@W1+b1)@W2+b2
        gemm(stream, SX, SLD, 0, msg_phi_w1 + (size_t)r * D * D, D,
             msg_phi_b1 + (size_t)r * D, H, D, 0, N, D, D, FBIAS | FSILU);
        gemm(stream, H, D, 0, msg_phi_w2 + (size_t)r * D * D3, D3,
             msg_phi_b2 + (size_t)r * D3, P_, D3, 0, N, D, D3, FBIAS);
        // message: read Vc, write Vs (= Vc + dv); S += ds
        hipLaunchKernelGGL(message_csr_k, dim3((N + MSG_NPB - 1) / MSG_NPB),
                           dim3(256), 0, stream,
                           offs, COLs, RBFs, UFs, P_, Vc,
                           msg_filt_w + (size_t)r * EDIM * D3,
                           msg_filt_b + (size_t)r * D3, SX, Vs, N);
        { float* t = Vc; Vc = Vs; Vs = t; }
        float* Uv = Vs;   // dead buffer
        // update: Uv and Vv in one dispatch
        gemm2(stream, Vc, D3, D, upd_U + (size_t)r * D * D,
              upd_V + (size_t)r * D * D, D, Uv, V3, D3, D, N, D, D);
        hipLaunchKernelGGL(norm3_k, dim3((N * D + 255) / 256), dim3(256), 0, stream,
                           V3, SX, N * D);
        // a = silu([s|Vn]@w1+b1)@w2+b2  (single K=256 GEMM via SX layout)
        gemm(stream, SX, SLD, 0, upd_w1 + (size_t)r * 2 * D * D, D,
             upd_b1 + (size_t)r * D, H2, D, 0, N, 2 * D, D, FBIAS | FSILU);
        gemm(stream, H2, D, 0, upd_w2 + (size_t)r * D * D3, D3,
             upd_b2 + (size_t)r * D3, P_, D3, 0, N, D, D3, FBIAS);
        hipLaunchKernelGGL(upd_apply_k, dim3((N * D + 255) / 256), dim3(256), 0, stream,
                           Uv, V3, P_, SX, Vc, N * D);
    }

    for (int g = 0; g < NG; ++g) {
        float* Uv = Vs;
        gemm2(stream, Vc, D3, D, geb_wv1 + (size_t)g * D * D,
              geb_wv2 + (size_t)g * D * D, D, Uv, V3, D3, D, N, D, D);
        hipLaunchKernelGGL(norm3_k, dim3((N * D + 255) / 256), dim3(256), 0, stream,
                           V3, SX, N * D);
        gemm(stream, SX, SLD, 0, geb_w1 + (size_t)g * 2 * D * D, D,
             geb_b1 + (size_t)g * D, H2, D, 0, N, 2 * D, D, FBIAS | FSILU);
        gemm(stream, H2, D, 0, geb_w2 + (size_t)g * D * 2 * D, 2 * D,
             geb_b2 + (size_t)g * 2 * D, P_, 2 * D, 0, N, D, 2 * D, FBIAS);
        hipLaunchKernelGGL(geb_apply_k, dim3((N * D + 255) / 256), dim3(256), 0, stream,
                           P_, Uv, SX, Vc, N * D);
    }

    // readout
    gemm(stream, SX, SLD, 0, ro_w1, HROH, ro_b1, H2, HROH, 0, N, D, HROH,
         FBIAS | FSILU);
    hipMemsetAsync(out, 0, (size_t)NMOL * 4, stream);
    hipLaunchKernelGGL(readout_k, dim3((N + 255) / 256), dim3(256), 0, stream,
                       H2, ro_w2, ro_b2, batch, out, N);
}

// Round 5
// 936.395 us; speedup vs baseline: 1.8422x; 1.0463x over previous
//
#include <hip/hip_runtime.h>

typedef __attribute__((ext_vector_type(4))) float f32x4;
typedef __attribute__((ext_vector_type(8))) short short8;

#define D 128
#define D3 384
#define SLD 256   // S buffer row stride: [s | Vn]
#define EDIM 20
#define NR 3
#define NG 3
#define CUTOFF 5.0f
#define NNODES 10000
#define NEDGES 160000
#define NMOL 500
#define HROH 64
#define PI_F 3.14159265358979323846f

#define FBIAS 1
#define FSILU 2
#define FBF16O 4

static __device__ __forceinline__ float silu_f(float x) {
    return x / (1.0f + expf(-x));
}

// bf16 helpers (round-to-nearest-even)
static __device__ __forceinline__ ushort f2bf(float x) {
    uint u = __float_as_uint(x);
    uint r = (u + 0x7fffu + ((u >> 16) & 1u)) >> 16;
    return (ushort)r;
}
static __device__ __forceinline__ float bf2f(ushort h) {
    return __uint_as_float((uint)h << 16);
}

#define TLR 64
#define TLC 64
#define KC 32
#define APAD 40
#define BPAD 36

// ---------------------------------------------------------------------------
// MFMA bf16x3 GEMM: C[n,m] = act(A[n,:] @ W[:,m] + bias[m])
// FBF16O: write bf16 to Cbf instead of f32 to C.
// ---------------------------------------------------------------------------
__global__ __launch_bounds__(256) void gemm_k(
    const float* __restrict__ A, int lda,
    const float* __restrict__ W, int ldw,
    const float* __restrict__ bias,
    float* __restrict__ C, ushort* __restrict__ Cbf, int ldc,
    int N, int K, int flags)
{
    const int n0 = blockIdx.x * TLR;
    const int m0 = blockIdx.y * TLC;
    __shared__ ushort Ah[TLR * APAD], Al[TLR * APAD];
    __shared__ ushort Bh[TLC * BPAD], Bl[TLC * BPAD];   // transposed: [col][k]
    const int tid = threadIdx.x;
    const int arow = tid & 63;
    const int akq = (tid >> 6) * 4;
    const bool aok = (n0 + arow) < N;
    const float* Ar = A + (size_t)(n0 + arow) * lda;
    const int bk = tid >> 4;
    const int bm = (tid & 15) * 4;
    const float* Wp = W + m0 + bm;
    const int lane = tid & 63;
    const int wrow = (tid >> 6) * 16;
    const int fr = lane & 15;
    const int kg = lane >> 4;
    const ushort* aph = Ah + (wrow + fr) * APAD + kg * 8;
    const ushort* apl = Al + (wrow + fr) * APAD + kg * 8;

    f32x4 acc[4];
    #pragma unroll
    for (int t = 0; t < 4; ++t) acc[t] = (f32x4){0.f, 0.f, 0.f, 0.f};

    for (int k0 = 0; k0 < K; k0 += KC) {
        #pragma unroll
        for (int half = 0; half < 2; ++half) {
            int kk = akq + half * 16;
            float4 v = aok ? *(const float4*)(Ar + k0 + kk)
                           : make_float4(0.f, 0.f, 0.f, 0.f);
            ushort h0 = f2bf(v.x), h1 = f2bf(v.y), h2 = f2bf(v.z), h3 = f2bf(v.w);
            ushort l0 = f2bf(v.x - bf2f(h0)), l1 = f2bf(v.y - bf2f(h1));
            ushort l2 = f2bf(v.z - bf2f(h2)), l3 = f2bf(v.w - bf2f(h3));
            uint2 ph, pl;
            ph.x = (uint)h0 | ((uint)h1 << 16); ph.y = (uint)h2 | ((uint)h3 << 16);
            pl.x = (uint)l0 | ((uint)l1 << 16); pl.y = (uint)l2 | ((uint)l3 << 16);
            *(uint2*)(Ah + arow * APAD + kk) = ph;
            *(uint2*)(Al + arow * APAD + kk) = pl;
        }
        #pragma unroll
        for (int half = 0; half < 2; ++half) {
            int kk = bk + half * 16;
            float4 v = *(const float4*)(Wp + (size_t)(k0 + kk) * ldw);
            float vv[4] = {v.x, v.y, v.z, v.w};
            #pragma unroll
            for (int i = 0; i < 4; ++i) {
                ushort hh = f2bf(vv[i]);
                ushort ll = f2bf(vv[i] - bf2f(hh));
                Bh[(bm + i) * BPAD + kk] = hh;
                Bl[(bm + i) * BPAD + kk] = ll;
            }
        }
        __syncthreads();
        short8 ah = *(const short8*)aph;
        short8 al = *(const short8*)apl;
        #pragma unroll
        for (int t = 0; t < 4; ++t) {
            const ushort* bp = Bh + (t * 16 + fr) * BPAD + kg * 8;
            const ushort* bq = Bl + (t * 16 + fr) * BPAD + kg * 8;
            short8 bh, bl;
            ((uint2*)&bh)[0] = *(const uint2*)bp;
            ((uint2*)&bh)[1] = *(const uint2*)(bp + 4);
            ((uint2*)&bl)[0] = *(const uint2*)bq;
            ((uint2*)&bl)[1] = *(const uint2*)(bq + 4);
            acc[t] = __builtin_amdgcn_mfma_f32_16x16x32_bf16(ah, bh, acc[t], 0, 0, 0);
            acc[t] = __builtin_amdgcn_mfma_f32_16x16x32_bf16(al, bh, acc[t], 0, 0, 0);
            acc[t] = __builtin_amdgcn_mfma_f32_16x16x32_bf16(ah, bl, acc[t], 0, 0, 0);
        }
        __syncthreads();
    }
    #pragma unroll
    for (int t = 0; t < 4; ++t) {
        #pragma unroll
        for (int r = 0; r < 4; ++r) {
            int n = n0 + wrow + kg * 4 + r;
            if (n < N) {
                int m = m0 + t * 16 + fr;
                float val = acc[t][r];
                if (flags & FBIAS) val += bias[m];
                if (flags & FSILU) val = silu_f(val);
                if (flags & FBF16O) Cbf[(size_t)n * ldc + m] = f2bf(val);
                else                C[(size_t)n * ldc + m] = val;
            }
        }
    }
}

// ---------------------------------------------------------------------------
// uvn_k: fused Uv = v@WU, Vv = v@WV (3 coords), Vn = |Vv| -> SX[:,128:],
// DOT = <Uv,Vv> (if WITHDOT). Vv itself is never materialized.
// Block: 64 rows x 64 cols (grid.y in 0..1), 6 accumulator tiles.
// ---------------------------------------------------------------------------
template <bool WITHDOT>
__global__ __launch_bounds__(256) void uvn_k(
    const float* __restrict__ A,     // [N,3,D] stride D3
    const float* __restrict__ WU, const float* __restrict__ WV,   // [D,D]
    float* __restrict__ Uv,          // [N,3,D]
    float* __restrict__ DOT,         // [N,D]
    float* __restrict__ SX, int N)
{
    const int n0 = blockIdx.x * 64;
    const int m0 = blockIdx.y * 64;
    __shared__ ushort Ah[3][64 * APAD], Al[3][64 * APAD];
    __shared__ ushort Bh[2][64 * BPAD], Bl[2][64 * BPAD];
    const int tid = threadIdx.x;
    const int arow = tid & 63;
    const int akq = (tid >> 6) * 4;
    const bool aok = (n0 + arow) < N;
    const float* Ar = A + (size_t)(n0 + arow) * D3;
    const int bk = tid >> 4;
    const int bm = (tid & 15) * 4;
    const int lane = tid & 63;
    const int wrow = (tid >> 6) * 16;
    const int fr = lane & 15;
    const int kg = lane >> 4;

    f32x4 acc[3][2][4];
    #pragma unroll
    for (int c = 0; c < 3; ++c)
        #pragma unroll
        for (int s = 0; s < 2; ++s)
            #pragma unroll
            for (int t = 0; t < 4; ++t) acc[c][s][t] = (f32x4){0.f, 0.f, 0.f, 0.f};

    for (int k0 = 0; k0 < D; k0 += KC) {
        #pragma unroll
        for (int c = 0; c < 3; ++c) {
            #pragma unroll
            for (int half = 0; half < 2; ++half) {
                int kk = akq + half * 16;
                float4 v = aok ? *(const float4*)(Ar + c * D + k0 + kk)
                               : make_float4(0.f, 0.f, 0.f, 0.f);
                ushort h0 = f2bf(v.x), h1 = f2bf(v.y), h2 = f2bf(v.z), h3 = f2bf(v.w);
                ushort l0 = f2bf(v.x - bf2f(h0)), l1 = f2bf(v.y - bf2f(h1));
                ushort l2 = f2bf(v.z - bf2f(h2)), l3 = f2bf(v.w - bf2f(h3));
                uint2 ph, pl;
                ph.x = (uint)h0 | ((uint)h1 << 16); ph.y = (uint)h2 | ((uint)h3 << 16);
                pl.x = (uint)l0 | ((uint)l1 << 16); pl.y = (uint)l2 | ((uint)l3 << 16);
                *(uint2*)(&Ah[c][arow * APAD + kk]) = ph;
                *(uint2*)(&Al[c][arow * APAD + kk]) = pl;
            }
        }
        #pragma unroll
        for (int s = 0; s < 2; ++s) {
            const float* W = s ? WV : WU;
            #pragma unroll
            for (int half = 0; half < 2; ++half) {
                int kk = bk + half * 16;
                float4 v = *(const float4*)(W + (size_t)(k0 + kk) * D + m0 + bm);
                float vv[4] = {v.x, v.y, v.z, v.w};
                #pragma unroll
                for (int i = 0; i < 4; ++i) {
                    ushort hh = f2bf(vv[i]);
                    ushort ll = f2bf(vv[i] - bf2f(hh));
                    Bh[s][(bm + i) * BPAD + kk] = hh;
                    Bl[s][(bm + i) * BPAD + kk] = ll;
                }
            }
        }
        __syncthreads();
        short8 ah[3], al[3];
        #pragma unroll
        for (int c = 0; c < 3; ++c) {
            ah[c] = *(const short8*)(&Ah[c][(wrow + fr) * APAD + kg * 8]);
            al[c] = *(const short8*)(&Al[c][(wrow + fr) * APAD + kg * 8]);
        }
        #pragma unroll
        for (int t = 0; t < 4; ++t) {
            #pragma unroll
            for (int s = 0; s < 2; ++s) {
                const ushort* bp = &Bh[s][(t * 16 + fr) * BPAD + kg * 8];
                const ushort* bq = &Bl[s][(t * 16 + fr) * BPAD + kg * 8];
                short8 bh, bl;
                ((uint2*)&bh)[0] = *(const uint2*)bp;
                ((uint2*)&bh)[1] = *(const uint2*)(bp + 4);
                ((uint2*)&bl)[0] = *(const uint2*)bq;
                ((uint2*)&bl)[1] = *(const uint2*)(bq + 4);
                #pragma unroll
                for (int c = 0; c < 3; ++c) {
                    acc[c][s][t] = __builtin_amdgcn_mfma_f32_16x16x32_bf16(ah[c], bh, acc[c][s][t], 0, 0, 0);
                    acc[c][s][t] = __builtin_amdgcn_mfma_f32_16x16x32_bf16(al[c], bh, acc[c][s][t], 0, 0, 0);
                    acc[c][s][t] = __builtin_amdgcn_mfma_f32_16x16x32_bf16(ah[c], bl, acc[c][s][t], 0, 0, 0);
                }
            }
        }
        __syncthreads();
    }
    #pragma unroll
    for (int t = 0; t < 4; ++t) {
        #pragma unroll
        for (int r = 0; r < 4; ++r) {
            int n = n0 + wrow + kg * 4 + r;
            if (n < N) {
                int m = m0 + t * 16 + fr;
                float ux = acc[0][0][t][r], uy = acc[1][0][t][r], uz = acc[2][0][t][r];
                float vx = acc[0][1][t][r], vy = acc[1][1][t][r], vz = acc[2][1][t][r];
                float* up = Uv + (size_t)n * D3 + m;
                up[0]     = ux;
                up[D]     = uy;
                up[2 * D] = uz;
                SX[(size_t)n * SLD + D + m] =
                    sqrtf(fmaf(vx, vx, fmaf(vy, vy, fmaf(vz, vz, 1e-8f))));
                if (WITHDOT)
                    DOT[(size_t)n * D + m] = fmaf(ux, vx, fmaf(uy, vy, uz * vz));
            }
        }
    }
}

// ---------------------------------------------------------------------------
// s = h @ emb_w + emb_b   (K=5); S has row stride SLD
// ---------------------------------------------------------------------------
__global__ __launch_bounds__(256) void emb_k(
    const float* __restrict__ h, const float* __restrict__ w,
    const float* __restrict__ b, float* __restrict__ s, int total)
{
    int i = blockIdx.x * 256 + threadIdx.x;
    if (i >= total) return;
    int n = i >> 7, d = i & 127;
    float acc = b[d];
    #pragma unroll
    for (int k = 0; k < 5; ++k) acc = fmaf(h[n * 5 + k], w[k * D + d], acc);
    s[(size_t)n * SLD + d] = acc;
}

// ---------------------------------------------------------------------------
// CSR construction
// ---------------------------------------------------------------------------
__global__ __launch_bounds__(256) void hist_k(const int* __restrict__ ei,
                                              int* __restrict__ cnt, int E)
{
    int e = blockIdx.x * 256 + threadIdx.x;
    if (e < E) atomicAdd(&cnt[ei[e]], 1);
}

__global__ __launch_bounds__(256) void scan_k(const int* __restrict__ cnt,
                                              int* __restrict__ offs, int n)
{
    __shared__ int tmp[256];
    __shared__ int carry;
    if (threadIdx.x == 0) carry = 0;
    __syncthreads();
    for (int base = 0; base < n; base += 256) {
        int i = base + threadIdx.x;
        int v = (i < n) ? cnt[i] : 0;
        tmp[threadIdx.x] = v;
        __syncthreads();
        for (int off = 1; off < 256; off <<= 1) {
            int add = (threadIdx.x >= off) ? tmp[threadIdx.x - off] : 0;
            __syncthreads();
            tmp[threadIdx.x] += add;
            __syncthreads();
        }
        if (i < n) offs[i + 1] = carry + tmp[threadIdx.x];
        __syncthreads();
        if (threadIdx.x == 255) carry += tmp[255];
        __syncthreads();
    }
    if (threadIdx.x == 0) offs[0] = 0;
}

__global__ __launch_bounds__(256) void initnext_k(const int* __restrict__ offs,
                                                  int* __restrict__ next, int n)
{
    int i = blockIdx.x * 256 + threadIdx.x;
    if (i < n) next[i] = offs[i];
}

// ---------------------------------------------------------------------------
// Edge geometry written directly into CSR-sorted slots.
// ---------------------------------------------------------------------------
__global__ __launch_bounds__(256) void edge_pre_k(
    const int* __restrict__ ei, const float* __restrict__ pos,
    int* __restrict__ next, float* __restrict__ rbf_s,
    float* __restrict__ uf_s, int* __restrict__ col_s, int E)
{
    int e = blockIdx.x * 256 + threadIdx.x;
    if (e >= E) return;
    int r = ei[e], c = ei[E + e];
    float dx = pos[c * 3 + 0] - pos[r * 3 + 0];
    float dy = pos[c * 3 + 1] - pos[r * 3 + 1];
    float dz = pos[c * 3 + 2] - pos[r * 3 + 2];
    float dist = sqrtf(dx * dx + dy * dy + dz * dz);
    float d = fmaxf(dist, 1e-6f);
    float inv = 1.0f / d;
    int p = atomicAdd(&next[r], 1);
    col_s[p] = c;
    uf_s[p * 4 + 0] = dx * inv;
    uf_s[p * 4 + 1] = dy * inv;
    uf_s[p * 4 + 2] = dz * inv;
    uf_s[p * 4 + 3] = (d < CUTOFF) ? 0.5f * (cosf(PI_F * d / CUTOFF) + 1.0f) : 0.0f;
    float w = PI_F * d / CUTOFF;
    #pragma unroll
    for (int k = 1; k <= EDIM; ++k)
        rbf_s[(size_t)p * EDIM + (k - 1)] = sinf((float)k * w) * inv;
}

// ---------------------------------------------------------------------------
// CSR message pass v4: bf16 gathers (P, V mirrors), sequential edge arrays,
// register filter weights, 2-edge ILP, register accumulation.
// ---------------------------------------------------------------------------
#define MSG_NPB 4
__global__ __launch_bounds__(256) void message_csr_k(
    const int* __restrict__ offs, const int* __restrict__ col_s,
    const float* __restrict__ rbf_s, const float* __restrict__ uf_s,
    const ushort* __restrict__ Pbf, const float* __restrict__ Vold,
    const ushort* __restrict__ VbfOld,
    const float* __restrict__ Wf, const float* __restrict__ bf,
    float* __restrict__ S, float* __restrict__ Vnew,
    ushort* __restrict__ VbfNew, int N)
{
    const int sub = threadIdx.x >> 7;
    const int d = threadIdx.x & 127;
    float ws[EDIM], wvv[EDIM], wvw[EDIM];
    #pragma unroll
    for (int k = 0; k < EDIM; ++k) {
        ws[k]  = Wf[k * D3 + d];
        wvv[k] = Wf[k * D3 + D + d];
        wvw[k] = Wf[k * D3 + 2 * D + d];
    }
    const float bs = bf[d], bvv = bf[D + d], bvw = bf[2 * D + d];

    auto edge = [&](int j, float& ds, float& dvx, float& dvy, float& dvz) {
        float4 u4 = *(const float4*)(uf_s + (size_t)j * 4);
        int col = col_s[j];
        const float* rb = rbf_s + (size_t)j * EDIM;
        float4 r0 = *(const float4*)(rb);
        float4 r1 = *(const float4*)(rb + 4);
        float4 r2 = *(const float4*)(rb + 8);
        float4 r3 = *(const float4*)(rb + 12);
        float4 r4 = *(const float4*)(rb + 16);
        float rv[EDIM] = {r0.x, r0.y, r0.z, r0.w, r1.x, r1.y, r1.z, r1.w,
                          r2.x, r2.y, r2.z, r2.w, r3.x, r3.y, r3.z, r3.w,
                          r4.x, r4.y, r4.z, r4.w};
        float fs = bs, fvv = bvv, fvw = bvw;
        #pragma unroll
        for (int k = 0; k < EDIM; ++k) {
            fs  = fmaf(rv[k], ws[k], fs);
            fvv = fmaf(rv[k], wvv[k], fvv);
            fvw = fmaf(rv[k], wvw[k], fvw);
        }
        float fc = u4.w;
        const ushort* pc = Pbf + (size_t)col * D3;
        const ushort* vc = VbfOld + (size_t)col * D3;
        float xs  = bf2f(pc[d]) * fs * fc;
        float xvv = bf2f(pc[D + d]) * fvv * fc;
        float xvw = bf2f(pc[2 * D + d]) * fvw * fc;
        ds += xs;
        dvx = fmaf(xvv, bf2f(vc[d]),         fmaf(xvw, u4.x, dvx));
        dvy = fmaf(xvv, bf2f(vc[D + d]),     fmaf(xvw, u4.y, dvy));
        dvz = fmaf(xvv, bf2f(vc[2 * D + d]), fmaf(xvw, u4.z, dvz));
    };

    for (int it = 0; it < MSG_NPB / 2; ++it) {
        int n = blockIdx.x * MSG_NPB + it * 2 + sub;
        if (n >= N) return;   // no __syncthreads in kernel: safe
        float ds0 = 0.f, dx0 = 0.f, dy0 = 0.f, dz0 = 0.f;
        float ds1 = 0.f, dx1 = 0.f, dy1 = 0.f, dz1 = 0.f;
        const int j0 = offs[n], j1 = offs[n + 1];
        int j = j0;
        for (; j + 2 <= j1; j += 2) {
            edge(j, ds0, dx0, dy0, dz0);
            edge(j + 1, ds1, dx1, dy1, dz1);
        }
        if (j < j1) edge(j, ds0, dx0, dy0, dz0);
        S[(size_t)n * SLD + d] += ds0 + ds1;
        const float* vo = Vold + (size_t)n * D3;
        float* vn = Vnew + (size_t)n * D3;
        ushort* vb = VbfNew + (size_t)n * D3;
        float nx = vo[d] + dx0 + dx1;
        float ny = vo[D + d] + dy0 + dy1;
        float nz = vo[2 * D + d] + dz0 + dz1;
        vn[d] = nx;         vb[d] = f2bf(nx);
        vn[D + d] = ny;     vb[D + d] = f2bf(ny);
        vn[2 * D + d] = nz; vb[2 * D + d] = f2bf(nz);
    }
}

// s += a_ss + a_sv * DOT;  v += a_vv * Uv  (+ bf16 mirror refresh)
__global__ __launch_bounds__(256) void upd_apply_k(
    const float* __restrict__ U3, const float* __restrict__ DOT,
    const float* __restrict__ P, float* __restrict__ s,
    float* __restrict__ v, ushort* __restrict__ vbf, int total)
{
    int i = blockIdx.x * 256 + threadIdx.x;
    if (i >= total) return;
    int n = i >> 7, d = i & 127;
    const float* u = U3 + (size_t)n * D3;
    float ux = u[d], uy = u[D + d], uz = u[2 * D + d];
    const float* a = P + (size_t)n * D3;
    s[(size_t)n * SLD + d] += a[d] + a[D + d] * DOT[i];
    float avv = a[2 * D + d];
    float* vv = v + (size_t)n * D3;
    ushort* vb = vbf + (size_t)n * D3;
    float nx = fmaf(avv, ux, vv[d]);
    float ny = fmaf(avv, uy, vv[D + d]);
    float nz = fmaf(avv, uz, vv[2 * D + d]);
    vv[d] = nx;         vb[d] = f2bf(nx);
    vv[D + d] = ny;     vb[D + d] = f2bf(ny);
    vv[2 * D + d] = nz; vb[2 * D + d] = f2bf(nz);
}

// s = a[:, :D];  v = a[:, D:2D, None] * v1
__global__ __launch_bounds__(256) void geb_apply_k(
    const float* __restrict__ P, const float* __restrict__ U3,
    float* __restrict__ s, float* __restrict__ v, int total)
{
    int i = blockIdx.x * 256 + threadIdx.x;
    if (i >= total) return;
    int n = i >> 7, d = i & 127;
    const float* a = P + (size_t)n * 2 * D;
    s[(size_t)n * SLD + d] = a[d];
    float g = a[D + d];
    const float* u = U3 + (size_t)n * D3;
    float* vv = v + (size_t)n * D3;
    vv[d]         = g * u[d];
    vv[D + d]     = g * u[D + d];
    vv[2 * D + d] = g * u[2 * D + d];
}

// out[batch[n]] += hidden[n] @ ro_w2 + ro_b2
__global__ __launch_bounds__(256) void readout_k(
    const float* __restrict__ H2, const float* __restrict__ w2,
    const float* __restrict__ b2, const int* __restrict__ batch,
    float* __restrict__ out, int N)
{
    int n = blockIdx.x * 256 + threadIdx.x;
    if (n >= N) return;
    float acc = b2[0];
    const float* hrow = H2 + (size_t)n * HROH;
    #pragma unroll
    for (int k = 0; k < HROH; ++k) acc = fmaf(hrow[k], w2[k], acc);
    atomicAdd(out + batch[n], acc);
}

// ---------------------------------------------------------------------------

static inline void gemm(hipStream_t st, const float* A, int lda,
                        const float* W, int ldw, const float* bias,
                        float* C, ushort* Cbf, int ldc,
                        int N, int K, int M, int flags)
{
    dim3 g((N + TLR - 1) / TLR, M / TLC, 1);
    hipLaunchKernelGGL(gemm_k, g, dim3(256), 0, st,
                       A, lda, W, ldw, bias, C, Cbf, ldc, N, K, flags);
}

extern "C" void kernel_launch(void* const* d_in, const int* in_sizes, int n_in,
                              void* d_out, int out_size, void* d_ws, size_t ws_size,
                              hipStream_t stream)
{
    const float* h          = (const float*)d_in[0];
    const float* pos        = (const float*)d_in[1];
    const int*   ei         = (const int*)d_in[2];
    const int*   batch      = (const int*)d_in[3];
    const float* emb_w      = (const float*)d_in[4];
    const float* emb_b      = (const float*)d_in[5];
    const float* msg_phi_w1 = (const float*)d_in[6];
    const float* msg_phi_b1 = (const float*)d_in[7];
    const float* msg_phi_w2 = (const float*)d_in[8];
    const float* msg_phi_b2 = (const float*)d_in[9];
    const float* msg_filt_w = (const float*)d_in[10];
    const float* msg_filt_b = (const float*)d_in[11];
    const float* upd_U      = (const float*)d_in[12];
    const float* upd_V      = (const float*)d_in[13];
    const float* upd_w1     = (const float*)d_in[14];
    const float* upd_b1     = (const float*)d_in[15];
    const float* upd_w2     = (const float*)d_in[16];
    const float* upd_b2     = (const float*)d_in[17];
    const float* geb_wv1    = (const float*)d_in[18];
    const float* geb_wv2    = (const float*)d_in[19];
    const float* geb_w1     = (const float*)d_in[20];
    const float* geb_b1     = (const float*)d_in[21];
    const float* geb_w2     = (const float*)d_in[22];
    const float* geb_b2     = (const float*)d_in[23];
    const float* ro_w1      = (const float*)d_in[24];
    const float* ro_b1      = (const float*)d_in[25];
    const float* ro_w2      = (const float*)d_in[26];
    const float* ro_b2      = (const float*)d_in[27];
    float* out = (float*)d_out;

    const int N = NNODES, E = NEDGES;

    char* p = (char*)d_ws;
    auto carve = [&](size_t bytes) {
        char* r = p;
        p += (bytes + 255) & ~(size_t)255;
        return r;
    };
    float*  SX   = (float*)carve((size_t)N * SLD * 4);   // [s | Vn]
    float*  VA   = (float*)carve((size_t)N * D3 * 4);
    float*  VB   = (float*)carve((size_t)N * D3 * 4);
    float*  P_   = (float*)carve((size_t)N * D3 * 4);    // 'a' buffer; Pbf aliases
    ushort* Pbf  = (ushort*)P_;                          // bf16 phi (message phase)
    ushort* VBFa = (ushort*)carve((size_t)N * D3 * 2);
    ushort* VBFb = (ushort*)carve((size_t)N * D3 * 2);
    float*  H    = (float*)carve((size_t)N * D * 4);     // phi hidden / DOT
    float*  H2   = (float*)carve((size_t)N * D * 4);
    float*  RBFs = (float*)carve((size_t)E * EDIM * 4);
    float*  UFs  = (float*)carve((size_t)E * 4 * 4);
    int*    COLs = (int*)carve((size_t)E * 4);
    int*    offs = (int*)carve((size_t)(N + 1) * 4);
    int*    nxt  = (int*)carve((size_t)N * 4);

    // init: s = emb(h), v = 0 (+mirror), CSR offsets, sorted edge geometry
    hipMemsetAsync(VA, 0, (size_t)N * D3 * 4, stream);
    hipMemsetAsync(VBFa, 0, (size_t)N * D3 * 2, stream);
    hipLaunchKernelGGL(emb_k, dim3((N * D + 255) / 256), dim3(256), 0, stream,
                       h, emb_w, emb_b, SX, N * D);
    hipMemsetAsync(nxt, 0, (size_t)N * 4, stream);
    hipLaunchKernelGGL(hist_k, dim3((E + 255) / 256), dim3(256), 0, stream, ei, nxt, E);
    hipLaunchKernelGGL(scan_k, dim3(1), dim3(256), 0, stream, nxt, offs, N);
    hipLaunchKernelGGL(initnext_k, dim3((N + 255) / 256), dim3(256), 0, stream,
                       offs, nxt, N);
    hipLaunchKernelGGL(edge_pre_k, dim3((E + 255) / 256), dim3(256), 0, stream,
                       ei, pos, nxt, RBFs, UFs, COLs, E);

    float*  Vc = VA;   ushort* VbfC = VBFa;
    float*  Vs = VB;   ushort* VbfS = VBFb;

    for (int r = 0; r < NR; ++r) {
        // phi = silu(s@W1+b1)@W2+b2  -> bf16 P
        gemm(stream, SX, SLD, msg_phi_w1 + (size_t)r * D * D, D,
             msg_phi_b1 + (size_t)r * D, H, nullptr, D, N, D, D, FBIAS | FSILU);
        gemm(stream, H, D, msg_phi_w2 + (size_t)r * D * D3, D3,
             msg_phi_b2 + (size_t)r * D3, nullptr, Pbf, D3, N, D, D3,
             FBIAS | FBF16O);
        // message: read Vc (+mirror), write Vs (+mirror); S += ds
        hipLaunchKernelGGL(message_csr_k, dim3((N + MSG_NPB - 1) / MSG_NPB),
                           dim3(256), 0, stream,
                           offs, COLs, RBFs, UFs, Pbf, Vc, VbfC,
                           msg_filt_w + (size_t)r * EDIM * D3,
                           msg_filt_b + (size_t)r * D3, SX, Vs, VbfS, N);
        { float* t = Vc; Vc = Vs; Vs = t; }
        { ushort* t = VbfC; VbfC = VbfS; VbfS = t; }
        float* Uv = Vs;   // dead f32 buffer
        // fused Uv/Vn/DOT
        hipLaunchKernelGGL(HIP_KERNEL_NAME(uvn_k<true>),
                           dim3((N + 63) / 64, 2), dim3(256), 0, stream,
                           Vc, upd_U + (size_t)r * D * D,
                           upd_V + (size_t)r * D * D, Uv, H, SX, N);
        // a = silu([s|Vn]@w1+b1)@w2+b2  (single K=256 GEMM)
        gemm(stream, SX, SLD, upd_w1 + (size_t)r * 2 * D * D, D,
             upd_b1 + (size_t)r * D, H2, nullptr, D, N, 2 * D, D, FBIAS | FSILU);
        gemm(stream, H2, D, upd_w2 + (size_t)r * D * D3, D3,
             upd_b2 + (size_t)r * D3, P_, nullptr, D3, N, D, D3, FBIAS);
        hipLaunchKernelGGL(upd_apply_k, dim3((N * D + 255) / 256), dim3(256), 0,
                           stream, Uv, H, P_, SX, Vc, VbfC, N * D);
    }

    for (int g = 0; g < NG; ++g) {
        float* Uv = Vs;
        hipLaunchKernelGGL(HIP_KERNEL_NAME(uvn_k<false>),
                           dim3((N + 63) / 64, 2), dim3(256), 0, stream,
                           Vc, geb_wv1 + (size_t)g * D * D,
                           geb_wv2 + (size_t)g * D * D, Uv, nullptr, SX, N);
        gemm(stream, SX, SLD, geb_w1 + (size_t)g * 2 * D * D, D,
             geb_b1 + (size_t)g * D, H2, nullptr, D, N, 2 * D, D, FBIAS | FSILU);
        gemm(stream, H2, D, geb_w2 + (size_t)g * D * 2 * D, 2 * D,
             geb_b2 + (size_t)g * 2 * D, P_, nullptr, 2 * D, N, D, 2 * D, FBIAS);
        hipLaunchKernelGGL(geb_apply_k, dim3((N * D + 255) / 256), dim3(256), 0,
                           stream, P_, Uv, SX, Vc, N * D);
    }

    // readout
    gemm(stream, SX, SLD, ro_w1, HROH, ro_b1, H2, nullptr, HROH, N, D, HROH,
         FBIAS | FSILU);
    hipMemsetAsync(out, 0, (size_t)NMOL * 4, stream);
    hipLaunchKernelGGL(readout_k, dim3((N + 255) / 256), dim3(256), 0, stream,
                       H2, ro_w2, ro_b2, batch, out, N);
}